// Round 2
// baseline (1382.498 us; speedup 1.0000x reference)
//
#include <hip/hip_runtime.h>

#define BSZ 32
#define SLEN 512
#define CLEN 20
#define DMOD 256
#define NH 4
#define HDIM 64

// ---------------- embedding sum + positional encoding ----------------
__global__ __launch_bounds__(256) void k_embed(
    const int* __restrict__ seqs, const int* __restrict__ lengths,
    const float* __restrict__ emb, const float* __restrict__ bias,
    const float* __restrict__ pe, float* __restrict__ x) {
  const int row0 = blockIdx.x * 4;
  const int sub = threadIdx.x >> 6;
  const int lane = threadIdx.x & 63;
  const int row = row0 + sub;
  const int b = row >> 9, s = row & 511;
  __shared__ int codes[4][CLEN];
  if (threadIdx.x < 4 * CLEN)
    codes[threadIdx.x / CLEN][threadIdx.x % CLEN] = seqs[row0 * CLEN + threadIdx.x];
  __syncthreads();
  const int pos = (s < lengths[b]) ? (s + 1) : 0;
  const int d = lane * 4;
  float4 acc = *(const float4*)(bias + d);
  const float4 pv = *(const float4*)(pe + (size_t)pos * DMOD + d);
  acc.x += pv.x; acc.y += pv.y; acc.z += pv.z; acc.w += pv.w;
  #pragma unroll
  for (int c = 0; c < CLEN; ++c) {
    const float4 ev = *(const float4*)(emb + (size_t)codes[sub][c] * DMOD + d);
    acc.x += ev.x; acc.y += ev.y; acc.z += ev.z; acc.w += ev.w;
  }
  *(float4*)(x + (size_t)row * DMOD + d) = acc;
}

// ---------------- bit-pack attention mask: [32,512,512] int -> [32,512,16] u32 ----
__global__ __launch_bounds__(256) void k_maskpack(
    const int* __restrict__ masks, unsigned int* __restrict__ pk) {
  const int bq = blockIdx.x;                 // b*512 + q
  const int wv = threadIdx.x >> 6;           // wave 0..3
  const int lane = threadIdx.x & 63;
  #pragma unroll
  for (int p = 0; p < 2; ++p) {
    const int chunk = wv + p * 4;            // k-chunk of 64
    const int m = masks[(size_t)bq * SLEN + chunk * 64 + lane];
    const unsigned long long bal = __ballot(m != 0);
    if (lane == 0) {
      pk[(size_t)bq * 16 + chunk * 2]     = (unsigned int)bal;
      pk[(size_t)bq * 16 + chunk * 2 + 1] = (unsigned int)(bal >> 32);
    }
  }
}

// ---------------- C = A @ W^T (+res), A:[M,256], W:[256,256] ----------------
#define BM 128
#define BN 128
#define BK 16

__global__ __launch_bounds__(256, 2) void k_gemm(
    const float* __restrict__ A,
    const float* __restrict__ W0, const float* __restrict__ W1, const float* __restrict__ W2,
    float* __restrict__ C0, float* __restrict__ C1, float* __restrict__ C2,
    const float* __restrict__ res, int use_res) {
  const float* W; float* C;
  if (blockIdx.z == 0)      { W = W0; C = C0; }
  else if (blockIdx.z == 1) { W = W1; C = C1; }
  else                      { W = W2; C = C2; }
  const int m0 = blockIdx.x * BM;
  const int n0 = blockIdx.y * BN;
  const int tid = threadIdx.x;
  __shared__ float As[BK][BM + 4];
  __shared__ float Ws[BK][BN + 4];
  float acc[8][8] = {};
  const int tm = (tid >> 4) * 8;   // rows: broadcast within wave quarters
  const int tn = (tid & 15) * 8;   // cols: contiguous across lanes -> coalesced C stores
  const int sr = tid >> 1;         // staging row 0..127
  const int sc = (tid & 1) * 8;    // staging col 0 or 8
  float4 a0 = *(const float4*)(A + (size_t)(m0 + sr) * DMOD + sc);
  float4 a1 = *(const float4*)(A + (size_t)(m0 + sr) * DMOD + sc + 4);
  float4 w0 = *(const float4*)(W + (size_t)(n0 + sr) * DMOD + sc);
  float4 w1 = *(const float4*)(W + (size_t)(n0 + sr) * DMOD + sc + 4);
  for (int k0 = 0; k0 < DMOD; k0 += BK) {
    As[sc+0][sr]=a0.x; As[sc+1][sr]=a0.y; As[sc+2][sr]=a0.z; As[sc+3][sr]=a0.w;
    As[sc+4][sr]=a1.x; As[sc+5][sr]=a1.y; As[sc+6][sr]=a1.z; As[sc+7][sr]=a1.w;
    Ws[sc+0][sr]=w0.x; Ws[sc+1][sr]=w0.y; Ws[sc+2][sr]=w0.z; Ws[sc+3][sr]=w0.w;
    Ws[sc+4][sr]=w1.x; Ws[sc+5][sr]=w1.y; Ws[sc+6][sr]=w1.z; Ws[sc+7][sr]=w1.w;
    __syncthreads();
    if (k0 + BK < DMOD) {  // prefetch next slab, latency hidden under compute
      a0 = *(const float4*)(A + (size_t)(m0 + sr) * DMOD + k0 + BK + sc);
      a1 = *(const float4*)(A + (size_t)(m0 + sr) * DMOD + k0 + BK + sc + 4);
      w0 = *(const float4*)(W + (size_t)(n0 + sr) * DMOD + k0 + BK + sc);
      w1 = *(const float4*)(W + (size_t)(n0 + sr) * DMOD + k0 + BK + sc + 4);
    }
    #pragma unroll
    for (int k = 0; k < BK; ++k) {
      float a[8], w[8];
      *(float4*)(a)     = *(const float4*)&As[k][tm];
      *(float4*)(a + 4) = *(const float4*)&As[k][tm + 4];
      *(float4*)(w)     = *(const float4*)&Ws[k][tn];
      *(float4*)(w + 4) = *(const float4*)&Ws[k][tn + 4];
      #pragma unroll
      for (int i = 0; i < 8; ++i)
        #pragma unroll
        for (int j = 0; j < 8; ++j)
          acc[i][j] += a[i] * w[j];
    }
    __syncthreads();
  }
  #pragma unroll
  for (int i = 0; i < 8; ++i) {
    float* crow = C + (size_t)(m0 + tm + i) * DMOD + n0 + tn;
    float o[8];
    if (use_res) {
      const float* rrow = res + (size_t)(m0 + tm + i) * DMOD + n0 + tn;
      const float4 r0 = *(const float4*)rrow;
      const float4 r1 = *(const float4*)(rrow + 4);
      o[0]=acc[i][0]+r0.x; o[1]=acc[i][1]+r0.y; o[2]=acc[i][2]+r0.z; o[3]=acc[i][3]+r0.w;
      o[4]=acc[i][4]+r1.x; o[5]=acc[i][5]+r1.y; o[6]=acc[i][6]+r1.z; o[7]=acc[i][7]+r1.w;
    } else {
      #pragma unroll
      for (int j = 0; j < 8; ++j) o[j] = acc[i][j];
    }
    *(float4*)crow       = *(float4*)o;
    *(float4*)(crow + 4) = *(float4*)(o + 4);
  }
}

// ---------------- fused attention per (b,h,q-tile of 64) ----------------
// Q/K/V views: contiguous [512,64] blocks at (b*4+h)*512*64 (faithful reshape).
// softmax as exp(e)/sum(exp(e)) (no max-sub; |e|~O(1), math-identical).
__global__ __launch_bounds__(256, 2) void k_attn(
    const float* __restrict__ Q, const float* __restrict__ K, const float* __restrict__ V,
    const unsigned int* __restrict__ pk, float* __restrict__ O) {
  const int bh = blockIdx.y;
  const int b = bh >> 2, h = bh & 3;
  const int q0 = blockIdx.x * 64;
  const float* Qb = Q + (size_t)bh * SLEN * HDIM;
  const float* Kb = K + (size_t)bh * SLEN * HDIM;
  const float* Vb = V + (size_t)bh * SLEN * HDIM;
  __shared__ float Qs[64][HDIM + 4];   // [q][d]
  __shared__ float Ks[64][HDIM + 4];   // [k][d]
  __shared__ float Vs[64][HDIM + 4];   // [k][d]
  __shared__ float Es[64][64 + 4];     // exp(e) [k][q]
  __shared__ float Ps[16][64 + 4];     // partial row sums
  __shared__ unsigned int Ms[64][2];   // packed mask bits for this (q-row, k-chunk)
  __shared__ float lsum[64];
  const int tid = threadIdx.x;
  const int qg = (tid & 15) * 4;
  const int kg = (tid >> 4) * 4;
  {
    const int r = tid >> 2;
    const int d0 = (tid & 3) * 16;
    const float* src = Qb + (size_t)(q0 + r) * HDIM + d0;
    #pragma unroll
    for (int p = 0; p < 4; ++p)
      *(float4*)&Qs[r][d0 + 4 * p] = *(const float4*)(src + 4 * p);
  }
  if (tid < 64) lsum[tid] = 0.f;
  float oacc[4][4] = {};
  for (int kc = 0; kc < SLEN; kc += 64) {
    {
      const int r = tid >> 2;
      const int d0 = (tid & 3) * 16;
      const float* ksrc = Kb + (size_t)(kc + r) * HDIM + d0;
      const float* vsrc = Vb + (size_t)(kc + r) * HDIM + d0;
      #pragma unroll
      for (int p = 0; p < 4; ++p) {
        *(float4*)&Ks[r][d0 + 4 * p] = *(const float4*)(ksrc + 4 * p);
        *(float4*)&Vs[r][d0 + 4 * p] = *(const float4*)(vsrc + 4 * p);
      }
      if (tid < 128)
        Ms[tid >> 1][tid & 1] =
            pk[((size_t)(b << 9) + q0 + (tid >> 1)) * 16 + (kc >> 5) + (tid & 1)];
    }
    __syncthreads();
    unsigned long long mrow[4];
    #pragma unroll
    for (int i = 0; i < 4; ++i)
      mrow[i] = (((unsigned long long)Ms[qg + i][1]) << 32) | Ms[qg + i][0];
    // phase i: e[4q][4k] = sum_d q*k  (inner product, float4 frags)
    float e[4][4] = {};
    #pragma unroll
    for (int d4 = 0; d4 < HDIM; d4 += 4) {
      float4 qv[4], kv[4];
      #pragma unroll
      for (int i = 0; i < 4; ++i) qv[i] = *(const float4*)&Qs[qg + i][d4];
      #pragma unroll
      for (int j = 0; j < 4; ++j) kv[j] = *(const float4*)&Ks[kg + j][d4];
      #pragma unroll
      for (int i = 0; i < 4; ++i)
        #pragma unroll
        for (int j = 0; j < 4; ++j)
          e[i][j] += qv[i].x * kv[j].x + qv[i].y * kv[j].y +
                     qv[i].z * kv[j].z + qv[i].w * kv[j].w;
    }
    float psum[4] = {0.f, 0.f, 0.f, 0.f};
    #pragma unroll
    for (int j = 0; j < 4; ++j) {
      float4 ev;
      ev.x = ((mrow[0] >> (kg + j)) & 1ULL) ? __expf(e[0][j] * 0.125f) : 0.f;
      ev.y = ((mrow[1] >> (kg + j)) & 1ULL) ? __expf(e[1][j] * 0.125f) : 0.f;
      ev.z = ((mrow[2] >> (kg + j)) & 1ULL) ? __expf(e[2][j] * 0.125f) : 0.f;
      ev.w = ((mrow[3] >> (kg + j)) & 1ULL) ? __expf(e[3][j] * 0.125f) : 0.f;
      *(float4*)&Es[kg + j][qg] = ev;
      psum[0] += ev.x; psum[1] += ev.y; psum[2] += ev.z; psum[3] += ev.w;
    }
    *(float4*)&Ps[tid >> 4][qg] = make_float4(psum[0], psum[1], psum[2], psum[3]);
    __syncthreads();
    if (tid < 64) {
      float s = lsum[tid];
      #pragma unroll
      for (int g = 0; g < 16; ++g) s += Ps[g][tid];
      lsum[tid] = s;
    }
    // phase ii: O[4q][4d] += E^T @ V over this chunk
    #pragma unroll 8
    for (int kk = 0; kk < 64; ++kk) {
      float ee[4], vv[4];
      *(float4*)ee = *(const float4*)&Es[kk][qg];
      *(float4*)vv = *(const float4*)&Vs[kk][kg];
      #pragma unroll
      for (int i = 0; i < 4; ++i)
        #pragma unroll
        for (int j = 0; j < 4; ++j)
          oacc[i][j] += ee[i] * vv[j];
    }
    __syncthreads();
  }
  // normalize + write transposed layout: O[b, s, h*64 + d]
  #pragma unroll
  for (int i = 0; i < 4; ++i) {
    const float inv = 1.0f / lsum[qg + i];
    float ov[4];
    #pragma unroll
    for (int j = 0; j < 4; ++j) ov[j] = oacc[i][j] * inv;
    *(float4*)(O + ((size_t)(b * SLEN + q0 + qg + i)) * DMOD + h * HDIM + kg) = *(float4*)ov;
  }
}

// ---------------- layer norm + zero invalid rows ----------------
__global__ __launch_bounds__(256) void k_ln(
    const float* __restrict__ Y, const int* __restrict__ lengths,
    const float* __restrict__ g, const float* __restrict__ bb,
    float* __restrict__ out) {
  const int row = blockIdx.x * 4 + (threadIdx.x >> 6);
  const int lane = threadIdx.x & 63;
  const int b = row >> 9, s = row & 511;
  const float* yr = Y + (size_t)row * DMOD;
  float v[4];
  *(float4*)v = *(const float4*)(yr + lane * 4);
  float sum = v[0] + v[1] + v[2] + v[3];
  #pragma unroll
  for (int off = 32; off > 0; off >>= 1) sum += __shfl_xor(sum, off);
  const float mu = sum * (1.0f / DMOD);
  float vs = 0.f;
  #pragma unroll
  for (int i = 0; i < 4; ++i) { const float dx = v[i] - mu; vs += dx * dx; }
  #pragma unroll
  for (int off = 32; off > 0; off >>= 1) vs += __shfl_xor(vs, off);
  const float inv = rsqrtf(vs * (1.0f / DMOD) + 1e-5f);
  const bool valid = s < lengths[b];
  float gg[4], bv[4], ov[4];
  *(float4*)gg = *(const float4*)(g + lane * 4);
  *(float4*)bv = *(const float4*)(bb + lane * 4);
  #pragma unroll
  for (int i = 0; i < 4; ++i)
    ov[i] = valid ? ((v[i] - mu) * inv * gg[i] + bv[i]) : 0.f;
  *(float4*)(out + (size_t)row * DMOD + lane * 4) = *(float4*)ov;
}

// ---------------- triangular temporal pooling, 4 bins fused, s-chunked ----------------
__global__ __launch_bounds__(256) void k_pool(
    const float* __restrict__ X, const int* __restrict__ lengths,
    float* __restrict__ Up) {
  const int b = blockIdx.x;
  const int c = blockIdx.y;          // s-chunk of 128
  const int d = threadIdx.x;
  const float inv4 = 4.0f / (float)lengths[b];
  float a0 = 0.f, a1 = 0.f, a2 = 0.f, a3 = 0.f;
  for (int s = c * 128; s < c * 128 + 128; ++s) {
    const float sv = (float)(s + 1) * inv4;
    const float xv = X[((size_t)b * SLEN + s) * DMOD + d];
    float t;
    t = 1.0f - fabsf(sv - 1.0f) * 0.25f; a0 += t * t * xv;
    t = 1.0f - fabsf(sv - 2.0f) * 0.25f; a1 += t * t * xv;
    t = 1.0f - fabsf(sv - 3.0f) * 0.25f; a2 += t * t * xv;
    t = 1.0f - fabsf(sv - 4.0f) * 0.25f; a3 += t * t * xv;
  }
  float* up = Up + (((size_t)b * 4 + c) * 4) * DMOD + d;   // [b][c][m][d]
  up[0 * DMOD] = a0; up[1 * DMOD] = a1; up[2 * DMOD] = a2; up[3 * DMOD] = a3;
}

// ---------------- final [32,1024] @ [1024,2]^T + bias (sums chunk partials) ----------
__global__ __launch_bounds__(256) void k_out(
    const float* __restrict__ Up, const float* __restrict__ ow,
    const float* __restrict__ ob, float* __restrict__ out) {
  const int tid = threadIdx.x;
  const int pair = tid >> 2;       // (b,i)
  const int part = tid & 3;        // == bin m
  const int b = pair >> 1, i = pair & 1;
  const float* upb = Up + ((size_t)b * 16 + part) * DMOD;   // [b][c][part][*]
  const float* wb = ow + (size_t)i * 1024 + part * DMOD;
  float acc = 0.f;
  for (int d = 0; d < DMOD; d += 4) {
    const float4 u0 = *(const float4*)(upb + d);
    const float4 u1 = *(const float4*)(upb + 4 * DMOD + d);
    const float4 u2 = *(const float4*)(upb + 8 * DMOD + d);
    const float4 u3 = *(const float4*)(upb + 12 * DMOD + d);
    const float4 w = *(const float4*)(wb + d);
    acc += (u0.x + u1.x + u2.x + u3.x) * w.x + (u0.y + u1.y + u2.y + u3.y) * w.y +
           (u0.z + u1.z + u2.z + u3.z) * w.z + (u0.w + u1.w + u2.w + u3.w) * w.w;
  }
  acc += __shfl_xor(acc, 1);
  acc += __shfl_xor(acc, 2);
  if (part == 0) out[b * 2 + i] = acc + ob[i];
}

extern "C" void kernel_launch(void* const* d_in, const int* in_sizes, int n_in,
                              void* d_out, int out_size, void* d_ws, size_t ws_size,
                              hipStream_t stream) {
  const int* seqs     = (const int*)d_in[0];
  const int* masks    = (const int*)d_in[1];
  const int* lengths  = (const int*)d_in[2];
  const float* emb    = (const float*)d_in[5];
  const float* bias   = (const float*)d_in[6];
  const float* pe     = (const float*)d_in[7];
  const float* Wq     = (const float*)d_in[8];
  const float* Wk     = (const float*)d_in[9];
  const float* Wv     = (const float*)d_in[10];
  const float* Wfc    = (const float*)d_in[11];
  const float* ln_g   = (const float*)d_in[12];
  const float* ln_b   = (const float*)d_in[13];
  const float* out_w  = (const float*)d_in[14];
  const float* out_b  = (const float*)d_in[15];
  float* outp = (float*)d_out;

  float* ws = (float*)d_ws;
  const size_t NT = (size_t)BSZ * SLEN;     // 16384 rows
  float* x = ws;                            // embed+pe output (residual)
  float* q = x + NT * DMOD;
  float* k = q + NT * DMOD;
  float* v = k + NT * DMOD;
  float* o = v + NT * DMOD;                 // attention out, final layout
  float* y = o + NT * DMOD;                 // fc + res, then LN in place
  // overlap (stream-ordered, lifetimes disjoint):
  unsigned int* pk = (unsigned int*)y;      // packed mask: used before y is written
  float* Up = x;                            // pool partials: used after x is dead

  k_embed<<<NT / 4, 256, 0, stream>>>(seqs, lengths, emb, bias, pe, x);
  k_maskpack<<<BSZ * SLEN, 256, 0, stream>>>(masks, pk);
  k_gemm<<<dim3(NT / BM, DMOD / BN, 3), 256, 0, stream>>>(
      x, Wq, Wk, Wv, q, k, v, nullptr, 0);
  k_attn<<<dim3(SLEN / 64, BSZ * NH), 256, 0, stream>>>(q, k, v, pk, o);
  k_gemm<<<dim3(NT / BM, DMOD / BN, 1), 256, 0, stream>>>(
      o, Wfc, Wfc, Wfc, y, y, y, x, 1);
  k_ln<<<NT / 4, 256, 0, stream>>>(y, lengths, ln_g, ln_b, y);
  k_pool<<<dim3(BSZ, 4), 256, 0, stream>>>(y, lengths, Up);
  k_out<<<1, 256, 0, stream>>>(Up, out_w, out_b, outp);
}

// Round 3
// 460.414 us; speedup vs baseline: 3.0027x; 3.0027x over previous
//
#include <hip/hip_runtime.h>

#define BSZ 32
#define SLEN 512
#define CLEN 20
#define DMOD 256
#define NH 4
#define HDIM 64

// ---------------- embedding sum + positional encoding ----------------
__global__ __launch_bounds__(256) void k_embed(
    const int* __restrict__ seqs, const int* __restrict__ lengths,
    const float* __restrict__ emb, const float* __restrict__ bias,
    const float* __restrict__ pe, float* __restrict__ x) {
  const int row0 = blockIdx.x * 4;
  const int sub = threadIdx.x >> 6;
  const int lane = threadIdx.x & 63;
  const int row = row0 + sub;
  const int b = row >> 9, s = row & 511;
  __shared__ int codes[4][CLEN];
  if (threadIdx.x < 4 * CLEN)
    codes[threadIdx.x / CLEN][threadIdx.x % CLEN] = seqs[row0 * CLEN + threadIdx.x];
  __syncthreads();
  const int pos = (s < lengths[b]) ? (s + 1) : 0;
  const int d = lane * 4;
  float4 acc = *(const float4*)(bias + d);
  const float4 pv = *(const float4*)(pe + (size_t)pos * DMOD + d);
  acc.x += pv.x; acc.y += pv.y; acc.z += pv.z; acc.w += pv.w;
  #pragma unroll
  for (int c = 0; c < CLEN; ++c) {
    const float4 ev = *(const float4*)(emb + (size_t)codes[sub][c] * DMOD + d);
    acc.x += ev.x; acc.y += ev.y; acc.z += ev.z; acc.w += ev.w;
  }
  *(float4*)(x + (size_t)row * DMOD + d) = acc;
}

// ---------------- bit-pack attention mask: [32,512,512] int -> [32,512,16] u32 ----
__global__ __launch_bounds__(256) void k_maskpack(
    const int* __restrict__ masks, unsigned int* __restrict__ pk) {
  const int bq = blockIdx.x;                 // b*512 + q
  const int wv = threadIdx.x >> 6;           // wave 0..3
  const int lane = threadIdx.x & 63;
  #pragma unroll
  for (int p = 0; p < 2; ++p) {
    const int chunk = wv + p * 4;            // k-chunk of 64
    const int m = masks[(size_t)bq * SLEN + chunk * 64 + lane];
    const unsigned long long bal = __ballot(m != 0);
    if (lane == 0) {
      pk[(size_t)bq * 16 + chunk * 2]     = (unsigned int)bal;
      pk[(size_t)bq * 16 + chunk * 2 + 1] = (unsigned int)(bal >> 32);
    }
  }
}

// ---------------- C = A @ W^T (+res), A:[M,256], W:[256,256] ----------------
#define BM 128
#define BN 128
#define BK 16

__global__ __launch_bounds__(256, 2) void k_gemm(
    const float* __restrict__ A,
    const float* __restrict__ W0, const float* __restrict__ W1, const float* __restrict__ W2,
    float* __restrict__ C0, float* __restrict__ C1, float* __restrict__ C2,
    const float* __restrict__ res, int use_res) {
  const float* W; float* C;
  if (blockIdx.z == 0)      { W = W0; C = C0; }
  else if (blockIdx.z == 1) { W = W1; C = C1; }
  else                      { W = W2; C = C2; }
  const int m0 = blockIdx.x * BM;
  const int n0 = blockIdx.y * BN;
  const int tid = threadIdx.x;
  __shared__ float As[BK][BM + 4];
  __shared__ float Ws[BK][BN + 4];
  float acc[8][8] = {};
  const int tm = (tid >> 4) * 8;
  const int tn = (tid & 15) * 8;
  const int sr = tid >> 1;
  const int sc = (tid & 1) * 8;
  float4 a0 = *(const float4*)(A + (size_t)(m0 + sr) * DMOD + sc);
  float4 a1 = *(const float4*)(A + (size_t)(m0 + sr) * DMOD + sc + 4);
  float4 w0 = *(const float4*)(W + (size_t)(n0 + sr) * DMOD + sc);
  float4 w1 = *(const float4*)(W + (size_t)(n0 + sr) * DMOD + sc + 4);
  for (int k0 = 0; k0 < DMOD; k0 += BK) {
    As[sc+0][sr]=a0.x; As[sc+1][sr]=a0.y; As[sc+2][sr]=a0.z; As[sc+3][sr]=a0.w;
    As[sc+4][sr]=a1.x; As[sc+5][sr]=a1.y; As[sc+6][sr]=a1.z; As[sc+7][sr]=a1.w;
    Ws[sc+0][sr]=w0.x; Ws[sc+1][sr]=w0.y; Ws[sc+2][sr]=w0.z; Ws[sc+3][sr]=w0.w;
    Ws[sc+4][sr]=w1.x; Ws[sc+5][sr]=w1.y; Ws[sc+6][sr]=w1.z; Ws[sc+7][sr]=w1.w;
    __syncthreads();
    if (k0 + BK < DMOD) {
      a0 = *(const float4*)(A + (size_t)(m0 + sr) * DMOD + k0 + BK + sc);
      a1 = *(const float4*)(A + (size_t)(m0 + sr) * DMOD + k0 + BK + sc + 4);
      w0 = *(const float4*)(W + (size_t)(n0 + sr) * DMOD + k0 + BK + sc);
      w1 = *(const float4*)(W + (size_t)(n0 + sr) * DMOD + k0 + BK + sc + 4);
    }
    #pragma unroll
    for (int k = 0; k < BK; ++k) {
      float a[8], w[8];
      *(float4*)(a)     = *(const float4*)&As[k][tm];
      *(float4*)(a + 4) = *(const float4*)&As[k][tm + 4];
      *(float4*)(w)     = *(const float4*)&Ws[k][tn];
      *(float4*)(w + 4) = *(const float4*)&Ws[k][tn + 4];
      #pragma unroll
      for (int i = 0; i < 8; ++i)
        #pragma unroll
        for (int j = 0; j < 8; ++j)
          acc[i][j] += a[i] * w[j];
    }
    __syncthreads();
  }
  #pragma unroll
  for (int i = 0; i < 8; ++i) {
    float* crow = C + (size_t)(m0 + tm + i) * DMOD + n0 + tn;
    float o[8];
    if (use_res) {
      const float* rrow = res + (size_t)(m0 + tm + i) * DMOD + n0 + tn;
      const float4 r0 = *(const float4*)rrow;
      const float4 r1 = *(const float4*)(rrow + 4);
      o[0]=acc[i][0]+r0.x; o[1]=acc[i][1]+r0.y; o[2]=acc[i][2]+r0.z; o[3]=acc[i][3]+r0.w;
      o[4]=acc[i][4]+r1.x; o[5]=acc[i][5]+r1.y; o[6]=acc[i][6]+r1.z; o[7]=acc[i][7]+r1.w;
    } else {
      #pragma unroll
      for (int j = 0; j < 8; ++j) o[j] = acc[i][j];
    }
    *(float4*)crow       = *(float4*)o;
    *(float4*)(crow + 4) = *(float4*)(o + 4);
  }
}

// ---------------- fused attention per (b,h,q-tile of 64) ----------------
// Round-1-proven phase i (transposed LDS, 4x4 micro). Phase ii remapped to
// 8q x 8d micro-tiles with 4 wave-specialized k-quarter replicas, reduced
// through LDS once at the end. Mask via packed bits (pk).
__global__ __launch_bounds__(256, 2) void k_attn(
    const float* __restrict__ Q, const float* __restrict__ K, const float* __restrict__ V,
    const unsigned int* __restrict__ pk, float* __restrict__ O) {
  const int bh = blockIdx.y;
  const int b = bh >> 2, h = bh & 3;
  const int q0 = blockIdx.x * 64;
  const float* Qb = Q + (size_t)bh * SLEN * HDIM;
  const float* Kb = K + (size_t)bh * SLEN * HDIM;
  const float* Vb = V + (size_t)bh * SLEN * HDIM;
  __shared__ float Qs[HDIM][64 + 4];   // [d][q] transposed
  __shared__ float Ks[HDIM][64 + 4];   // [d][k] transposed
  __shared__ float Vs[64][HDIM + 4];   // [k][d]
  __shared__ float Es[64][64 + 4];     // exp(e) [k][q]; reused as O-accum [q][d]
  __shared__ float Ps[16][64 + 4];     // partial row sums
  __shared__ unsigned int Ms[64][2];
  __shared__ float lsum[64];
  const int tid = threadIdx.x;
  const int qg = (tid & 15) * 4;       // phase-i q base
  const int kg = (tid >> 4) * 4;       // phase-i k base
  const int q8 = (tid & 7) * 8;        // phase-ii q base
  const int d8 = ((tid >> 3) & 7) * 8; // phase-ii d base
  const int rep = tid >> 6;            // phase-ii k-quarter (wave-uniform)
  {
    const int d = tid & 63;
    const int qb4 = tid >> 6;
    #pragma unroll
    for (int p = 0; p < 16; ++p) {
      const int qq = qb4 + p * 4;
      Qs[d][qq] = Qb[(size_t)(q0 + qq) * HDIM + d];
    }
  }
  if (tid < 64) lsum[tid] = 0.f;
  float oacc[8][8] = {};
  for (int kc = 0; kc < SLEN; kc += 64) {
    {
      const int d = tid & 63;
      const int kb4 = tid >> 6;
      #pragma unroll
      for (int p = 0; p < 16; ++p) {
        const int kk = kb4 + p * 4;
        Ks[d][kk] = Kb[(size_t)(kc + kk) * HDIM + d];
      }
      #pragma unroll
      for (int p = 0; p < 4; ++p) {
        const int lin = tid + p * 256;
        const int kk = lin >> 4;
        const int d4 = (lin & 15) * 4;
        *(float4*)&Vs[kk][d4] = *(const float4*)(Vb + (size_t)(kc + kk) * HDIM + d4);
      }
      if (tid < 128)
        Ms[tid >> 1][tid & 1] =
            pk[((size_t)(b << 9) + q0 + (tid >> 1)) * 16 + (kc >> 5) + (tid & 1)];
    }
    __syncthreads();
    unsigned long long mrow[4];
    #pragma unroll
    for (int i = 0; i < 4; ++i)
      mrow[i] = (((unsigned long long)Ms[qg + i][1]) << 32) | Ms[qg + i][0];
    // phase i (round-1 structure): e[4q][4k] = sum_d q*k
    float e[4][4] = {};
    #pragma unroll 8
    for (int d = 0; d < HDIM; ++d) {
      float aq[4], ak[4];
      *(float4*)aq = *(const float4*)&Qs[d][qg];
      *(float4*)ak = *(const float4*)&Ks[d][kg];
      #pragma unroll
      for (int i = 0; i < 4; ++i)
        #pragma unroll
        for (int j = 0; j < 4; ++j)
          e[i][j] += aq[i] * ak[j];
    }
    float psum[4] = {0.f, 0.f, 0.f, 0.f};
    #pragma unroll
    for (int j = 0; j < 4; ++j) {
      float4 ev;
      ev.x = ((mrow[0] >> (kg + j)) & 1ULL) ? __expf(e[0][j] * 0.125f) : 0.f;
      ev.y = ((mrow[1] >> (kg + j)) & 1ULL) ? __expf(e[1][j] * 0.125f) : 0.f;
      ev.z = ((mrow[2] >> (kg + j)) & 1ULL) ? __expf(e[2][j] * 0.125f) : 0.f;
      ev.w = ((mrow[3] >> (kg + j)) & 1ULL) ? __expf(e[3][j] * 0.125f) : 0.f;
      *(float4*)&Es[kg + j][qg] = ev;
      psum[0] += ev.x; psum[1] += ev.y; psum[2] += ev.z; psum[3] += ev.w;
    }
    *(float4*)&Ps[tid >> 4][qg] = make_float4(psum[0], psum[1], psum[2], psum[3]);
    __syncthreads();
    if (tid < 64) {
      float s = lsum[tid];
      #pragma unroll
      for (int g = 0; g < 16; ++g) s += Ps[g][tid];
      lsum[tid] = s;
    }
    // phase ii: 8q x 8d, this wave handles k in [rep*16, rep*16+16)
    const int kbase = rep * 16;
    #pragma unroll 4
    for (int t = 0; t < 16; ++t) {
      const int kk = kbase + t;
      float ee[8], vv[8];
      *(float4*)(ee)     = *(const float4*)&Es[kk][q8];
      *(float4*)(ee + 4) = *(const float4*)&Es[kk][q8 + 4];
      *(float4*)(vv)     = *(const float4*)&Vs[kk][d8];
      *(float4*)(vv + 4) = *(const float4*)&Vs[kk][d8 + 4];
      #pragma unroll
      for (int i = 0; i < 8; ++i)
        #pragma unroll
        for (int j = 0; j < 8; ++j)
          oacc[i][j] += ee[i] * vv[j];
    }
    __syncthreads();
  }
  // reduce the 4 k-quarter replicas into Es (reused as O accum [q][d])
  #pragma unroll
  for (int r = 0; r < 4; ++r) {
    if (rep == r) {
      #pragma unroll
      for (int i = 0; i < 8; ++i) {
        if (r == 0) {
          *(float4*)&Es[q8 + i][d8] =
              make_float4(oacc[i][0], oacc[i][1], oacc[i][2], oacc[i][3]);
          *(float4*)&Es[q8 + i][d8 + 4] =
              make_float4(oacc[i][4], oacc[i][5], oacc[i][6], oacc[i][7]);
        } else {
          float4 t0 = *(const float4*)&Es[q8 + i][d8];
          float4 t1 = *(const float4*)&Es[q8 + i][d8 + 4];
          t0.x += oacc[i][0]; t0.y += oacc[i][1]; t0.z += oacc[i][2]; t0.w += oacc[i][3];
          t1.x += oacc[i][4]; t1.y += oacc[i][5]; t1.z += oacc[i][6]; t1.w += oacc[i][7];
          *(float4*)&Es[q8 + i][d8]     = t0;
          *(float4*)&Es[q8 + i][d8 + 4] = t1;
        }
      }
    }
    __syncthreads();
  }
  // normalize + write transposed layout: O[b, s, h*64 + d]
  {
    const int qq = tid >> 2;
    const int dB = (tid & 3) * 16;
    const float inv = 1.0f / lsum[qq];
    float* orow = O + ((size_t)(b * SLEN + q0 + qq)) * DMOD + h * HDIM + dB;
    #pragma unroll
    for (int p = 0; p < 4; ++p) {
      float4 t = *(const float4*)&Es[qq][dB + 4 * p];
      t.x *= inv; t.y *= inv; t.z *= inv; t.w *= inv;
      *(float4*)(orow + 4 * p) = t;
    }
  }
}

// ---------------- layer norm + zero invalid rows ----------------
__global__ __launch_bounds__(256) void k_ln(
    const float* __restrict__ Y, const int* __restrict__ lengths,
    const float* __restrict__ g, const float* __restrict__ bb,
    float* __restrict__ out) {
  const int row = blockIdx.x * 4 + (threadIdx.x >> 6);
  const int lane = threadIdx.x & 63;
  const int b = row >> 9, s = row & 511;
  const float* yr = Y + (size_t)row * DMOD;
  float v[4];
  *(float4*)v = *(const float4*)(yr + lane * 4);
  float sum = v[0] + v[1] + v[2] + v[3];
  #pragma unroll
  for (int off = 32; off > 0; off >>= 1) sum += __shfl_xor(sum, off);
  const float mu = sum * (1.0f / DMOD);
  float vs = 0.f;
  #pragma unroll
  for (int i = 0; i < 4; ++i) { const float dx = v[i] - mu; vs += dx * dx; }
  #pragma unroll
  for (int off = 32; off > 0; off >>= 1) vs += __shfl_xor(vs, off);
  const float inv = rsqrtf(vs * (1.0f / DMOD) + 1e-5f);
  const bool valid = s < lengths[b];
  float gg[4], bv[4], ov[4];
  *(float4*)gg = *(const float4*)(g + lane * 4);
  *(float4*)bv = *(const float4*)(bb + lane * 4);
  #pragma unroll
  for (int i = 0; i < 4; ++i)
    ov[i] = valid ? ((v[i] - mu) * inv * gg[i] + bv[i]) : 0.f;
  *(float4*)(out + (size_t)row * DMOD + lane * 4) = *(float4*)ov;
}

// ---------------- triangular temporal pooling, 4 bins fused, s-chunked ----------------
__global__ __launch_bounds__(256) void k_pool(
    const float* __restrict__ X, const int* __restrict__ lengths,
    float* __restrict__ Up) {
  const int b = blockIdx.x;
  const int c = blockIdx.y;          // s-chunk of 128
  const int d = threadIdx.x;
  const float inv4 = 4.0f / (float)lengths[b];
  float a0 = 0.f, a1 = 0.f, a2 = 0.f, a3 = 0.f;
  for (int s = c * 128; s < c * 128 + 128; ++s) {
    const float sv = (float)(s + 1) * inv4;
    const float xv = X[((size_t)b * SLEN + s) * DMOD + d];
    float t;
    t = 1.0f - fabsf(sv - 1.0f) * 0.25f; a0 += t * t * xv;
    t = 1.0f - fabsf(sv - 2.0f) * 0.25f; a1 += t * t * xv;
    t = 1.0f - fabsf(sv - 3.0f) * 0.25f; a2 += t * t * xv;
    t = 1.0f - fabsf(sv - 4.0f) * 0.25f; a3 += t * t * xv;
  }
  float* up = Up + (((size_t)b * 4 + c) * 4) * DMOD + d;   // [b][c][m][d]
  up[0 * DMOD] = a0; up[1 * DMOD] = a1; up[2 * DMOD] = a2; up[3 * DMOD] = a3;
}

// ---------------- final [32,1024] @ [1024,2]^T + bias (sums chunk partials) ----------
__global__ __launch_bounds__(256) void k_out(
    const float* __restrict__ Up, const float* __restrict__ ow,
    const float* __restrict__ ob, float* __restrict__ out) {
  const int tid = threadIdx.x;
  const int pair = tid >> 2;       // (b,i)
  const int part = tid & 3;        // == bin m
  const int b = pair >> 1, i = pair & 1;
  const float* upb = Up + ((size_t)b * 16 + part) * DMOD;
  const float* wb = ow + (size_t)i * 1024 + part * DMOD;
  float acc = 0.f;
  for (int d = 0; d < DMOD; d += 4) {
    const float4 u0 = *(const float4*)(upb + d);
    const float4 u1 = *(const float4*)(upb + 4 * DMOD + d);
    const float4 u2 = *(const float4*)(upb + 8 * DMOD + d);
    const float4 u3 = *(const float4*)(upb + 12 * DMOD + d);
    const float4 w = *(const float4*)(wb + d);
    acc += (u0.x + u1.x + u2.x + u3.x) * w.x + (u0.y + u1.y + u2.y + u3.y) * w.y +
           (u0.z + u1.z + u2.z + u3.z) * w.z + (u0.w + u1.w + u2.w + u3.w) * w.w;
  }
  acc += __shfl_xor(acc, 1);
  acc += __shfl_xor(acc, 2);
  if (part == 0) out[b * 2 + i] = acc + ob[i];
}

extern "C" void kernel_launch(void* const* d_in, const int* in_sizes, int n_in,
                              void* d_out, int out_size, void* d_ws, size_t ws_size,
                              hipStream_t stream) {
  const int* seqs     = (const int*)d_in[0];
  const int* masks    = (const int*)d_in[1];
  const int* lengths  = (const int*)d_in[2];
  const float* emb    = (const float*)d_in[5];
  const float* bias   = (const float*)d_in[6];
  const float* pe     = (const float*)d_in[7];
  const float* Wq     = (const float*)d_in[8];
  const float* Wk     = (const float*)d_in[9];
  const float* Wv     = (const float*)d_in[10];
  const float* Wfc    = (const float*)d_in[11];
  const float* ln_g   = (const float*)d_in[12];
  const float* ln_b   = (const float*)d_in[13];
  const float* out_w  = (const float*)d_in[14];
  const float* out_b  = (const float*)d_in[15];
  float* outp = (float*)d_out;

  float* ws = (float*)d_ws;
  const size_t NT = (size_t)BSZ * SLEN;     // 16384 rows
  float* x = ws;                            // embed+pe output (residual)
  float* q = x + NT * DMOD;
  float* k = q + NT * DMOD;
  float* v = k + NT * DMOD;
  float* o = v + NT * DMOD;                 // attention out, final layout
  float* y = o + NT * DMOD;                 // fc + res, then LN in place
  unsigned int* pk = (unsigned int*)y;      // packed mask: dead before y is written
  float* Up = x;                            // pool partials: used after x is dead

  k_embed<<<NT / 4, 256, 0, stream>>>(seqs, lengths, emb, bias, pe, x);
  k_maskpack<<<BSZ * SLEN, 256, 0, stream>>>(masks, pk);
  k_gemm<<<dim3(NT / BM, DMOD / BN, 3), 256, 0, stream>>>(
      x, Wq, Wk, Wv, q, k, v, nullptr, 0);
  k_attn<<<dim3(SLEN / 64, BSZ * NH), 256, 0, stream>>>(q, k, v, pk, o);
  k_gemm<<<dim3(NT / BM, DMOD / BN, 1), 256, 0, stream>>>(
      o, Wfc, Wfc, Wfc, y, y, y, x, 1);
  k_ln<<<NT / 4, 256, 0, stream>>>(y, lengths, ln_g, ln_b, y);
  k_pool<<<dim3(BSZ, 4), 256, 0, stream>>>(y, lengths, Up);
  k_out<<<1, 256, 0, stream>>>(Up, out_w, out_b, outp);
}

// Round 5
// 418.090 us; speedup vs baseline: 3.3067x; 1.1012x over previous
//
#include <hip/hip_runtime.h>

#define BSZ 32
#define SLEN 512
#define CLEN 20
#define DMOD 256
#define NH 4
#define HDIM 64

typedef _Float16 half8 __attribute__((ext_vector_type(8)));
typedef _Float16 half4 __attribute__((ext_vector_type(4)));
typedef float float4v __attribute__((ext_vector_type(4)));

// ---------------- embedding sum + positional encoding (+ fp16 hi/lo split) -----
__global__ __launch_bounds__(256) void k_embed(
    const int* __restrict__ seqs, const int* __restrict__ lengths,
    const float* __restrict__ emb, const float* __restrict__ bias,
    const float* __restrict__ pe, float* __restrict__ x,
    _Float16* __restrict__ xh, _Float16* __restrict__ xl) {
  const int row0 = blockIdx.x * 4;
  const int sub = threadIdx.x >> 6;
  const int lane = threadIdx.x & 63;
  const int row = row0 + sub;
  const int b = row >> 9, s = row & 511;
  __shared__ int codes[4][CLEN];
  if (threadIdx.x < 4 * CLEN)
    codes[threadIdx.x / CLEN][threadIdx.x % CLEN] = seqs[row0 * CLEN + threadIdx.x];
  __syncthreads();
  const int pos = (s < lengths[b]) ? (s + 1) : 0;
  const int d = lane * 4;
  float4 acc = *(const float4*)(bias + d);
  const float4 pv = *(const float4*)(pe + (size_t)pos * DMOD + d);
  acc.x += pv.x; acc.y += pv.y; acc.z += pv.z; acc.w += pv.w;
  #pragma unroll
  for (int c = 0; c < CLEN; ++c) {
    const float4 ev = *(const float4*)(emb + (size_t)codes[sub][c] * DMOD + d);
    acc.x += ev.x; acc.y += ev.y; acc.z += ev.z; acc.w += ev.w;
  }
  const size_t off = (size_t)row * DMOD + d;
  *(float4*)(x + off) = acc;
  float a[4] = {acc.x, acc.y, acc.z, acc.w};
  half4 hv, lv;
  #pragma unroll
  for (int i = 0; i < 4; ++i) {
    hv[i] = (_Float16)a[i];
    lv[i] = (_Float16)(a[i] - (float)hv[i]);
  }
  *(half4*)(xh + off) = hv;
  *(half4*)(xl + off) = lv;
}

// ---------------- split 4 weight matrices [256x256] fp32 -> fp16 hi/lo ---------
__global__ __launch_bounds__(256) void k_wsplit(
    const float* __restrict__ W0, const float* __restrict__ W1,
    const float* __restrict__ W2, const float* __restrict__ W3,
    _Float16* __restrict__ wh, _Float16* __restrict__ wl) {
  const int z = blockIdx.y;
  const float* W = (z == 0) ? W0 : (z == 1) ? W1 : (z == 2) ? W2 : W3;
  const int idx = (blockIdx.x * 256 + threadIdx.x) * 8;
  float v[8];
  *(float4*)v = *(const float4*)(W + idx);
  *(float4*)(v + 4) = *(const float4*)(W + idx + 4);
  half8 h, l;
  #pragma unroll
  for (int i = 0; i < 8; ++i) {
    h[i] = (_Float16)v[i];
    l[i] = (_Float16)(v[i] - (float)h[i]);
  }
  *(half8*)(wh + (size_t)z * 65536 + idx) = h;
  *(half8*)(wl + (size_t)z * 65536 + idx) = l;
}

// ---------------- bit-pack attention mask: [32,512,512] int -> [32,512,16] u32 ----
__global__ __launch_bounds__(256) void k_maskpack(
    const int* __restrict__ masks, unsigned int* __restrict__ pk) {
  const int bq = blockIdx.x;
  const int wv = threadIdx.x >> 6;
  const int lane = threadIdx.x & 63;
  #pragma unroll
  for (int p = 0; p < 2; ++p) {
    const int chunk = wv + p * 4;
    const int m = masks[(size_t)bq * SLEN + chunk * 64 + lane];
    const unsigned long long bal = __ballot(m != 0);
    if (lane == 0) {
      pk[(size_t)bq * 16 + chunk * 2]     = (unsigned int)bal;
      pk[(size_t)bq * 16 + chunk * 2 + 1] = (unsigned int)(bal >> 32);
    }
  }
}

// ---------------- C = A @ W^T (+res) via split-fp16 MFMA ------------------------
// A given as hi/lo fp16 [M,256]; W as hi/lo fp16 [256,256] (z*65536 offset).
// 128x128 tile, 4 waves in 2x2, each wave 64x64 = 4x4 MFMA tiles of 16x16x32.
// LDS staged in frag-order: subtile(16 rows x 32 k) -> 64 lanes x 16B contiguous.
__global__ __launch_bounds__(256) void k_gemm_mfma(
    const _Float16* __restrict__ Ah, const _Float16* __restrict__ Al,
    const _Float16* __restrict__ Whb, const _Float16* __restrict__ Wlb,
    float* __restrict__ C0, float* __restrict__ C1, float* __restrict__ C2,
    const float* __restrict__ res, int use_res) {
  const int z = blockIdx.z;
  float* C = (z == 0) ? C0 : (z == 1) ? C1 : C2;
  const _Float16* wh = Whb + (size_t)z * 65536;
  const _Float16* wl = Wlb + (size_t)z * 65536;
  const int m0 = blockIdx.x * 128;
  const int n0 = blockIdx.y * 128;
  const int tid = threadIdx.x;
  const int lane = tid & 63;
  const int w = tid >> 6;
  const int wm = (w >> 1) * 4;   // m-subtile base
  const int wn = (w & 1) * 4;    // n-subtile base
  __shared__ half8 As_h[512], As_l[512], Ws_h[512], Ws_l[512];
  float4v acc[4][4];
  #pragma unroll
  for (int i = 0; i < 4; ++i)
    #pragma unroll
    for (int j = 0; j < 4; ++j)
      acc[i][j] = (float4v){0.f, 0.f, 0.f, 0.f};
  for (int k0 = 0; k0 < DMOD; k0 += 32) {
    #pragma unroll
    for (int p = 0; p < 2; ++p) {
      const int c = tid + p * 256;
      const int r = c & 127, qd = c >> 7;
      const int li = (r >> 4) * 64 + qd * 16 + (r & 15);
      const size_t ga = (size_t)(m0 + r) * DMOD + k0 + qd * 8;
      const size_t gw = (size_t)(n0 + r) * DMOD + k0 + qd * 8;
      As_h[li] = *(const half8*)(Ah + ga);
      As_l[li] = *(const half8*)(Al + ga);
      Ws_h[li] = *(const half8*)(wh + gw);
      Ws_l[li] = *(const half8*)(wl + gw);
    }
    __syncthreads();
    half8 afh[4], afl[4], wfh[4], wfl[4];
    #pragma unroll
    for (int i = 0; i < 4; ++i) {
      afh[i] = As_h[(wm + i) * 64 + lane];
      afl[i] = As_l[(wm + i) * 64 + lane];
      wfh[i] = Ws_h[(wn + i) * 64 + lane];
      wfl[i] = Ws_l[(wn + i) * 64 + lane];
    }
    #pragma unroll
    for (int i = 0; i < 4; ++i)
      #pragma unroll
      for (int j = 0; j < 4; ++j) {
        acc[i][j] = __builtin_amdgcn_mfma_f32_16x16x32_f16(afh[i], wfh[j], acc[i][j], 0, 0, 0);
        acc[i][j] = __builtin_amdgcn_mfma_f32_16x16x32_f16(afh[i], wfl[j], acc[i][j], 0, 0, 0);
        acc[i][j] = __builtin_amdgcn_mfma_f32_16x16x32_f16(afl[i], wfh[j], acc[i][j], 0, 0, 0);
      }
    __syncthreads();
  }
  // epilogue: C/D layout col=lane&15, row=(lane>>4)*4+reg  [m89-verified]
  const int cr = (lane >> 4) * 4;
  const int cc = lane & 15;
  #pragma unroll
  for (int i = 0; i < 4; ++i) {
    const int gr0 = m0 + (wm + i) * 16 + cr;
    #pragma unroll
    for (int j = 0; j < 4; ++j) {
      const int gc = n0 + (wn + j) * 16 + cc;
      #pragma unroll
      for (int r = 0; r < 4; ++r) {
        float val = acc[i][j][r];
        if (use_res) val += res[(size_t)(gr0 + r) * DMOD + gc];
        C[(size_t)(gr0 + r) * DMOD + gc] = val;
      }
    }
  }
}

// ---------------- fused attention per (b,h,q-tile of 64) — fp32 (round-3 proven) -
// Epilogue now emits hi/lo fp16 for the FC MFMA instead of fp32 O.
__global__ __launch_bounds__(256, 2) void k_attn(
    const float* __restrict__ Q, const float* __restrict__ K, const float* __restrict__ V,
    const unsigned int* __restrict__ pk,
    _Float16* __restrict__ oh, _Float16* __restrict__ ol) {
  const int bh = blockIdx.y;
  const int b = bh >> 2, h = bh & 3;
  const int q0 = blockIdx.x * 64;
  const float* Qb = Q + (size_t)bh * SLEN * HDIM;
  const float* Kb = K + (size_t)bh * SLEN * HDIM;
  const float* Vb = V + (size_t)bh * SLEN * HDIM;
  __shared__ float Qs[HDIM][64 + 4];
  __shared__ float Ks[HDIM][64 + 4];
  __shared__ float Vs[64][HDIM + 4];
  __shared__ float Es[64][64 + 4];
  __shared__ float Ps[16][64 + 4];
  __shared__ unsigned int Ms[64][2];
  __shared__ float lsum[64];
  const int tid = threadIdx.x;
  const int qg = (tid & 15) * 4;
  const int kg = (tid >> 4) * 4;
  const int q8 = (tid & 7) * 8;
  const int d8 = ((tid >> 3) & 7) * 8;
  const int rep = tid >> 6;
  {
    const int d = tid & 63;
    const int qb4 = tid >> 6;
    #pragma unroll
    for (int p = 0; p < 16; ++p) {
      const int qq = qb4 + p * 4;
      Qs[d][qq] = Qb[(size_t)(q0 + qq) * HDIM + d];
    }
  }
  if (tid < 64) lsum[tid] = 0.f;
  float oacc[8][8] = {};
  for (int kc = 0; kc < SLEN; kc += 64) {
    {
      const int d = tid & 63;
      const int kb4 = tid >> 6;
      #pragma unroll
      for (int p = 0; p < 16; ++p) {
        const int kk = kb4 + p * 4;
        Ks[d][kk] = Kb[(size_t)(kc + kk) * HDIM + d];
      }
      #pragma unroll
      for (int p = 0; p < 4; ++p) {
        const int lin = tid + p * 256;
        const int kk = lin >> 4;
        const int d4 = (lin & 15) * 4;
        *(float4*)&Vs[kk][d4] = *(const float4*)(Vb + (size_t)(kc + kk) * HDIM + d4);
      }
      if (tid < 128)
        Ms[tid >> 1][tid & 1] =
            pk[((size_t)(b << 9) + q0 + (tid >> 1)) * 16 + (kc >> 5) + (tid & 1)];
    }
    __syncthreads();
    unsigned long long mrow[4];
    #pragma unroll
    for (int i = 0; i < 4; ++i)
      mrow[i] = (((unsigned long long)Ms[qg + i][1]) << 32) | Ms[qg + i][0];
    float e[4][4] = {};
    #pragma unroll 8
    for (int d = 0; d < HDIM; ++d) {
      float aq[4], ak[4];
      *(float4*)aq = *(const float4*)&Qs[d][qg];
      *(float4*)ak = *(const float4*)&Ks[d][kg];
      #pragma unroll
      for (int i = 0; i < 4; ++i)
        #pragma unroll
        for (int j = 0; j < 4; ++j)
          e[i][j] += aq[i] * ak[j];
    }
    float psum[4] = {0.f, 0.f, 0.f, 0.f};
    #pragma unroll
    for (int j = 0; j < 4; ++j) {
      float4 ev;
      ev.x = ((mrow[0] >> (kg + j)) & 1ULL) ? __expf(e[0][j] * 0.125f) : 0.f;
      ev.y = ((mrow[1] >> (kg + j)) & 1ULL) ? __expf(e[1][j] * 0.125f) : 0.f;
      ev.z = ((mrow[2] >> (kg + j)) & 1ULL) ? __expf(e[2][j] * 0.125f) : 0.f;
      ev.w = ((mrow[3] >> (kg + j)) & 1ULL) ? __expf(e[3][j] * 0.125f) : 0.f;
      *(float4*)&Es[kg + j][qg] = ev;
      psum[0] += ev.x; psum[1] += ev.y; psum[2] += ev.z; psum[3] += ev.w;
    }
    *(float4*)&Ps[tid >> 4][qg] = make_float4(psum[0], psum[1], psum[2], psum[3]);
    __syncthreads();
    if (tid < 64) {
      float s = lsum[tid];
      #pragma unroll
      for (int g = 0; g < 16; ++g) s += Ps[g][tid];
      lsum[tid] = s;
    }
    const int kbase = rep * 16;
    #pragma unroll 4
    for (int t = 0; t < 16; ++t) {
      const int kk = kbase + t;
      float ee[8], vv[8];
      *(float4*)(ee)     = *(const float4*)&Es[kk][q8];
      *(float4*)(ee + 4) = *(const float4*)&Es[kk][q8 + 4];
      *(float4*)(vv)     = *(const float4*)&Vs[kk][d8];
      *(float4*)(vv + 4) = *(const float4*)&Vs[kk][d8 + 4];
      #pragma unroll
      for (int i = 0; i < 8; ++i)
        #pragma unroll
        for (int j = 0; j < 8; ++j)
          oacc[i][j] += ee[i] * vv[j];
    }
    __syncthreads();
  }
  #pragma unroll
  for (int r = 0; r < 4; ++r) {
    if (rep == r) {
      #pragma unroll
      for (int i = 0; i < 8; ++i) {
        if (r == 0) {
          *(float4*)&Es[q8 + i][d8] =
              make_float4(oacc[i][0], oacc[i][1], oacc[i][2], oacc[i][3]);
          *(float4*)&Es[q8 + i][d8 + 4] =
              make_float4(oacc[i][4], oacc[i][5], oacc[i][6], oacc[i][7]);
        } else {
          float4 t0 = *(const float4*)&Es[q8 + i][d8];
          float4 t1 = *(const float4*)&Es[q8 + i][d8 + 4];
          t0.x += oacc[i][0]; t0.y += oacc[i][1]; t0.z += oacc[i][2]; t0.w += oacc[i][3];
          t1.x += oacc[i][4]; t1.y += oacc[i][5]; t1.z += oacc[i][6]; t1.w += oacc[i][7];
          *(float4*)&Es[q8 + i][d8]     = t0;
          *(float4*)&Es[q8 + i][d8 + 4] = t1;
        }
      }
    }
    __syncthreads();
  }
  {
    const int qq = tid >> 2;
    const int dB = (tid & 3) * 16;
    const float inv = 1.0f / lsum[qq];
    const size_t base = ((size_t)(b * SLEN + q0 + qq)) * DMOD + h * HDIM + dB;
    #pragma unroll
    for (int p = 0; p < 4; ++p) {
      float4 t = *(const float4*)&Es[qq][dB + 4 * p];
      float tv[4] = {t.x * inv, t.y * inv, t.z * inv, t.w * inv};
      half4 hv, lv;
      #pragma unroll
      for (int i = 0; i < 4; ++i) {
        hv[i] = (_Float16)tv[i];
        lv[i] = (_Float16)(tv[i] - (float)hv[i]);
      }
      *(half4*)(oh + base + 4 * p) = hv;
      *(half4*)(ol + base + 4 * p) = lv;
    }
  }
}

// ---------------- layer norm + zero invalid rows ----------------
__global__ __launch_bounds__(256) void k_ln(
    const float* __restrict__ Y, const int* __restrict__ lengths,
    const float* __restrict__ g, const float* __restrict__ bb,
    float* __restrict__ out) {
  const int row = blockIdx.x * 4 + (threadIdx.x >> 6);
  const int lane = threadIdx.x & 63;
  const int b = row >> 9, s = row & 511;
  const float* yr = Y + (size_t)row * DMOD;
  float v[4];
  *(float4*)v = *(const float4*)(yr + lane * 4);
  float sum = v[0] + v[1] + v[2] + v[3];
  #pragma unroll
  for (int off = 32; off > 0; off >>= 1) sum += __shfl_xor(sum, off);
  const float mu = sum * (1.0f / DMOD);
  float vs = 0.f;
  #pragma unroll
  for (int i = 0; i < 4; ++i) { const float dx = v[i] - mu; vs += dx * dx; }
  #pragma unroll
  for (int off = 32; off > 0; off >>= 1) vs += __shfl_xor(vs, off);
  const float inv = rsqrtf(vs * (1.0f / DMOD) + 1e-5f);
  const bool valid = s < lengths[b];
  float gg[4], bv[4], ov[4];
  *(float4*)gg = *(const float4*)(g + lane * 4);
  *(float4*)bv = *(const float4*)(bb + lane * 4);
  #pragma unroll
  for (int i = 0; i < 4; ++i)
    ov[i] = valid ? ((v[i] - mu) * inv * gg[i] + bv[i]) : 0.f;
  *(float4*)(out + (size_t)row * DMOD + lane * 4) = *(float4*)ov;
}

// ---------------- triangular temporal pooling, 4 bins fused, s-chunked ----------
__global__ __launch_bounds__(256) void k_pool(
    const float* __restrict__ X, const int* __restrict__ lengths,
    float* __restrict__ Up) {
  const int b = blockIdx.x;
  const int c = blockIdx.y;
  const int d = threadIdx.x;
  const float inv4 = 4.0f / (float)lengths[b];
  float a0 = 0.f, a1 = 0.f, a2 = 0.f, a3 = 0.f;
  for (int s = c * 128; s < c * 128 + 128; ++s) {
    const float sv = (float)(s + 1) * inv4;
    const float xv = X[((size_t)b * SLEN + s) * DMOD + d];
    float t;
    t = 1.0f - fabsf(sv - 1.0f) * 0.25f; a0 += t * t * xv;
    t = 1.0f - fabsf(sv - 2.0f) * 0.25f; a1 += t * t * xv;
    t = 1.0f - fabsf(sv - 3.0f) * 0.25f; a2 += t * t * xv;
    t = 1.0f - fabsf(sv - 4.0f) * 0.25f; a3 += t * t * xv;
  }
  float* up = Up + (((size_t)b * 4 + c) * 4) * DMOD + d;
  up[0 * DMOD] = a0; up[1 * DMOD] = a1; up[2 * DMOD] = a2; up[3 * DMOD] = a3;
}

// ---------------- final [32,1024] @ [1024,2]^T + bias ---------------------------
__global__ __launch_bounds__(256) void k_out(
    const float* __restrict__ Up, const float* __restrict__ ow,
    const float* __restrict__ ob, float* __restrict__ out) {
  const int tid = threadIdx.x;
  const int pair = tid >> 2;
  const int part = tid & 3;
  const int b = pair >> 1, i = pair & 1;
  const float* upb = Up + ((size_t)b * 16 + part) * DMOD;
  const float* wb = ow + (size_t)i * 1024 + part * DMOD;
  float acc = 0.f;
  for (int d = 0; d < DMOD; d += 4) {
    const float4 u0 = *(const float4*)(upb + d);
    const float4 u1 = *(const float4*)(upb + 4 * DMOD + d);
    const float4 u2 = *(const float4*)(upb + 8 * DMOD + d);
    const float4 u3 = *(const float4*)(upb + 12 * DMOD + d);
    const float4 w = *(const float4*)(wb + d);
    acc += (u0.x + u1.x + u2.x + u3.x) * w.x + (u0.y + u1.y + u2.y + u3.y) * w.y +
           (u0.z + u1.z + u2.z + u3.z) * w.z + (u0.w + u1.w + u2.w + u3.w) * w.w;
  }
  acc += __shfl_xor(acc, 1);
  acc += __shfl_xor(acc, 2);
  if (part == 0) out[b * 2 + i] = acc + ob[i];
}

extern "C" void kernel_launch(void* const* d_in, const int* in_sizes, int n_in,
                              void* d_out, int out_size, void* d_ws, size_t ws_size,
                              hipStream_t stream) {
  const int* seqs     = (const int*)d_in[0];
  const int* masks    = (const int*)d_in[1];
  const int* lengths  = (const int*)d_in[2];
  const float* emb    = (const float*)d_in[5];
  const float* bias   = (const float*)d_in[6];
  const float* pe     = (const float*)d_in[7];
  const float* Wq     = (const float*)d_in[8];
  const float* Wk     = (const float*)d_in[9];
  const float* Wv     = (const float*)d_in[10];
  const float* Wfc    = (const float*)d_in[11];
  const float* ln_g   = (const float*)d_in[12];
  const float* ln_b   = (const float*)d_in[13];
  const float* out_w  = (const float*)d_in[14];
  const float* out_b  = (const float*)d_in[15];
  float* outp = (float*)d_out;

  float* ws = (float*)d_ws;
  const size_t NE = (size_t)BSZ * SLEN * DMOD;   // 4,194,304
  float* x = ws;
  float* q = x + NE;
  float* k = q + NE;
  float* v = k + NE;
  float* y = q;                               // reuse q after attention is done
  _Float16* xh = (_Float16*)(v + NE);
  _Float16* xl = xh + NE;
  _Float16* oh = xl + NE;
  _Float16* ol = oh + NE;
  _Float16* wh = ol + NE;                     // 4 * 65536 halfs
  _Float16* wl = wh + 4 * 65536;
  unsigned int* pk = (unsigned int*)(wl + 4 * 65536);
  float* Up = (float*)(pk + BSZ * SLEN * 16);

  k_embed<<<BSZ * SLEN / 4, 256, 0, stream>>>(seqs, lengths, emb, bias, pe, x, xh, xl);
  k_wsplit<<<dim3(32, 4), 256, 0, stream>>>(Wq, Wk, Wv, Wfc, wh, wl);
  k_maskpack<<<BSZ * SLEN, 256, 0, stream>>>(masks, pk);
  k_gemm_mfma<<<dim3(128, 2, 3), 256, 0, stream>>>(
      xh, xl, wh, wl, q, k, v, nullptr, 0);
  k_attn<<<dim3(SLEN / 64, BSZ * NH), 256, 0, stream>>>(q, k, v, pk, oh, ol);
  k_gemm_mfma<<<dim3(128, 2, 1), 256, 0, stream>>>(
      oh, ol, wh + 3 * 65536, wl + 3 * 65536, y, y, y, x, 1);
  k_ln<<<BSZ * SLEN / 4, 256, 0, stream>>>(y, lengths, ln_g, ln_b, y);
  k_pool<<<dim3(BSZ, 4), 256, 0, stream>>>(y, lengths, Up);
  k_out<<<1, 256, 0, stream>>>(Up, out_w, out_b, outp);
}

// Round 6
// 371.822 us; speedup vs baseline: 3.7182x; 1.1244x over previous
//
#include <hip/hip_runtime.h>

#define BSZ 32
#define SLEN 512
#define CLEN 20
#define DMOD 256
#define NH 4
#define HDIM 64

typedef _Float16 half8 __attribute__((ext_vector_type(8)));
typedef _Float16 half4 __attribute__((ext_vector_type(4)));
typedef float float4v __attribute__((ext_vector_type(4)));

#define MFMA16(a, b, c) __builtin_amdgcn_mfma_f32_16x16x32_f16(a, b, c, 0, 0, 0)

// ---------------- embedding sum + positional encoding (+ fp16 hi/lo split) -----
__global__ __launch_bounds__(256) void k_embed(
    const int* __restrict__ seqs, const int* __restrict__ lengths,
    const float* __restrict__ emb, const float* __restrict__ bias,
    const float* __restrict__ pe, float* __restrict__ x,
    _Float16* __restrict__ xh, _Float16* __restrict__ xl) {
  const int row0 = blockIdx.x * 4;
  const int sub = threadIdx.x >> 6;
  const int lane = threadIdx.x & 63;
  const int row = row0 + sub;
  const int b = row >> 9, s = row & 511;
  __shared__ int codes[4][CLEN];
  if (threadIdx.x < 4 * CLEN)
    codes[threadIdx.x / CLEN][threadIdx.x % CLEN] = seqs[row0 * CLEN + threadIdx.x];
  __syncthreads();
  const int pos = (s < lengths[b]) ? (s + 1) : 0;
  const int d = lane * 4;
  float4 acc = *(const float4*)(bias + d);
  const float4 pv = *(const float4*)(pe + (size_t)pos * DMOD + d);
  acc.x += pv.x; acc.y += pv.y; acc.z += pv.z; acc.w += pv.w;
  #pragma unroll
  for (int c = 0; c < CLEN; ++c) {
    const float4 ev = *(const float4*)(emb + (size_t)codes[sub][c] * DMOD + d);
    acc.x += ev.x; acc.y += ev.y; acc.z += ev.z; acc.w += ev.w;
  }
  const size_t off = (size_t)row * DMOD + d;
  *(float4*)(x + off) = acc;
  float a[4] = {acc.x, acc.y, acc.z, acc.w};
  half4 hv, lv;
  #pragma unroll
  for (int i = 0; i < 4; ++i) {
    hv[i] = (_Float16)a[i];
    lv[i] = (_Float16)(a[i] - (float)hv[i]);
  }
  *(half4*)(xh + off) = hv;
  *(half4*)(xl + off) = lv;
}

// ---------------- split 4 weight matrices [256x256] fp32 -> fp16 hi/lo ---------
__global__ __launch_bounds__(256) void k_wsplit(
    const float* __restrict__ W0, const float* __restrict__ W1,
    const float* __restrict__ W2, const float* __restrict__ W3,
    _Float16* __restrict__ wh, _Float16* __restrict__ wl) {
  const int z = blockIdx.y;
  const float* W = (z == 0) ? W0 : (z == 1) ? W1 : (z == 2) ? W2 : W3;
  const int idx = (blockIdx.x * 256 + threadIdx.x) * 8;
  float v[8];
  *(float4*)v = *(const float4*)(W + idx);
  *(float4*)(v + 4) = *(const float4*)(W + idx + 4);
  half8 h, l;
  #pragma unroll
  for (int i = 0; i < 8; ++i) {
    h[i] = (_Float16)v[i];
    l[i] = (_Float16)(v[i] - (float)h[i]);
  }
  *(half8*)(wh + (size_t)z * 65536 + idx) = h;
  *(half8*)(wl + (size_t)z * 65536 + idx) = l;
}

// ---------------- bit-pack attention mask: [32,512,512] int -> [32,512,16] u32 ----
__global__ __launch_bounds__(256) void k_maskpack(
    const int* __restrict__ masks, unsigned int* __restrict__ pk) {
  const int bq = blockIdx.x;
  const int wv = threadIdx.x >> 6;
  const int lane = threadIdx.x & 63;
  #pragma unroll
  for (int p = 0; p < 2; ++p) {
    const int chunk = wv + p * 4;
    const int m = masks[(size_t)bq * SLEN + chunk * 64 + lane];
    const unsigned long long bal = __ballot(m != 0);
    if (lane == 0) {
      pk[(size_t)bq * 16 + chunk * 2]     = (unsigned int)bal;
      pk[(size_t)bq * 16 + chunk * 2 + 1] = (unsigned int)(bal >> 32);
    }
  }
}

// ---------------- QKV GEMM via split-fp16 MFMA; writes hi/lo fp16 outputs -------
// z=0 -> q row-major, z=1 -> k row-major, z=2 -> v TRANSPOSED per-bh [d][s].
__global__ __launch_bounds__(256) void k_gemm_qkv(
    const _Float16* __restrict__ Ah, const _Float16* __restrict__ Al,
    const _Float16* __restrict__ Whb, const _Float16* __restrict__ Wlb,
    _Float16* __restrict__ qh, _Float16* __restrict__ ql,
    _Float16* __restrict__ kh, _Float16* __restrict__ kl,
    _Float16* __restrict__ vth, _Float16* __restrict__ vtl) {
  const int z = blockIdx.z;
  const _Float16* wh = Whb + (size_t)z * 65536;
  const _Float16* wl = Wlb + (size_t)z * 65536;
  const int m0 = blockIdx.x * 128;
  const int n0 = blockIdx.y * 128;
  const int tid = threadIdx.x;
  const int lane = tid & 63;
  const int w = tid >> 6;
  const int wm = (w >> 1) * 4;
  const int wn = (w & 1) * 4;
  __shared__ half8 As_h[512], As_l[512], Ws_h[512], Ws_l[512];
  float4v acc[4][4];
  #pragma unroll
  for (int i = 0; i < 4; ++i)
    #pragma unroll
    for (int j = 0; j < 4; ++j)
      acc[i][j] = (float4v){0.f, 0.f, 0.f, 0.f};
  for (int k0 = 0; k0 < DMOD; k0 += 32) {
    #pragma unroll
    for (int p = 0; p < 2; ++p) {
      const int c = tid + p * 256;
      const int r = c & 127, qd = c >> 7;
      const int li = (r >> 4) * 64 + qd * 16 + (r & 15);
      const size_t ga = (size_t)(m0 + r) * DMOD + k0 + qd * 8;
      const size_t gw = (size_t)(n0 + r) * DMOD + k0 + qd * 8;
      As_h[li] = *(const half8*)(Ah + ga);
      As_l[li] = *(const half8*)(Al + ga);
      Ws_h[li] = *(const half8*)(wh + gw);
      Ws_l[li] = *(const half8*)(wl + gw);
    }
    __syncthreads();
    half8 afh[4], afl[4], wfh[4], wfl[4];
    #pragma unroll
    for (int i = 0; i < 4; ++i) {
      afh[i] = As_h[(wm + i) * 64 + lane];
      afl[i] = As_l[(wm + i) * 64 + lane];
      wfh[i] = Ws_h[(wn + i) * 64 + lane];
      wfl[i] = Ws_l[(wn + i) * 64 + lane];
    }
    #pragma unroll
    for (int i = 0; i < 4; ++i)
      #pragma unroll
      for (int j = 0; j < 4; ++j) {
        acc[i][j] = MFMA16(afh[i], wfh[j], acc[i][j]);
        acc[i][j] = MFMA16(afh[i], wfl[j], acc[i][j]);
        acc[i][j] = MFMA16(afl[i], wfh[j], acc[i][j]);
      }
    __syncthreads();
  }
  const int cr = (lane >> 4) * 4;
  const int cc = lane & 15;
  #pragma unroll
  for (int i = 0; i < 4; ++i) {
    const int gm = m0 + (wm + i) * 16 + cr;
    #pragma unroll
    for (int j = 0; j < 4; ++j) {
      const int gc = n0 + (wn + j) * 16 + cc;
      #pragma unroll
      for (int r = 0; r < 4; ++r) {
        const float val = acc[i][j][r];
        const _Float16 hv = (_Float16)val;
        const _Float16 lv = (_Float16)(val - (float)hv);
        const size_t flat = (size_t)(gm + r) * DMOD + gc;
        if (z == 0)      { qh[flat] = hv; ql[flat] = lv; }
        else if (z == 1) { kh[flat] = hv; kl[flat] = lv; }
        else {
          // v[bh][s][d] -> vt[bh][d][s]
          const size_t idx = (flat & ~(size_t)32767) +
                             (size_t)(flat & 63) * 512 + ((flat >> 6) & 511);
          vth[idx] = hv; vtl[idx] = lv;
        }
      }
    }
  }
}

// ---------------- FC GEMM (fp32 out + residual), split-fp16 MFMA ----------------
__global__ __launch_bounds__(256) void k_gemm_fc(
    const _Float16* __restrict__ Ah, const _Float16* __restrict__ Al,
    const _Float16* __restrict__ wh, const _Float16* __restrict__ wl,
    float* __restrict__ C, const float* __restrict__ res) {
  const int m0 = blockIdx.x * 128;
  const int n0 = blockIdx.y * 128;
  const int tid = threadIdx.x;
  const int lane = tid & 63;
  const int w = tid >> 6;
  const int wm = (w >> 1) * 4;
  const int wn = (w & 1) * 4;
  __shared__ half8 As_h[512], As_l[512], Ws_h[512], Ws_l[512];
  float4v acc[4][4];
  #pragma unroll
  for (int i = 0; i < 4; ++i)
    #pragma unroll
    for (int j = 0; j < 4; ++j)
      acc[i][j] = (float4v){0.f, 0.f, 0.f, 0.f};
  for (int k0 = 0; k0 < DMOD; k0 += 32) {
    #pragma unroll
    for (int p = 0; p < 2; ++p) {
      const int c = tid + p * 256;
      const int r = c & 127, qd = c >> 7;
      const int li = (r >> 4) * 64 + qd * 16 + (r & 15);
      const size_t ga = (size_t)(m0 + r) * DMOD + k0 + qd * 8;
      const size_t gw = (size_t)(n0 + r) * DMOD + k0 + qd * 8;
      As_h[li] = *(const half8*)(Ah + ga);
      As_l[li] = *(const half8*)(Al + ga);
      Ws_h[li] = *(const half8*)(wh + gw);
      Ws_l[li] = *(const half8*)(wl + gw);
    }
    __syncthreads();
    half8 afh[4], afl[4], wfh[4], wfl[4];
    #pragma unroll
    for (int i = 0; i < 4; ++i) {
      afh[i] = As_h[(wm + i) * 64 + lane];
      afl[i] = As_l[(wm + i) * 64 + lane];
      wfh[i] = Ws_h[(wn + i) * 64 + lane];
      wfl[i] = Ws_l[(wn + i) * 64 + lane];
    }
    #pragma unroll
    for (int i = 0; i < 4; ++i)
      #pragma unroll
      for (int j = 0; j < 4; ++j) {
        acc[i][j] = MFMA16(afh[i], wfh[j], acc[i][j]);
        acc[i][j] = MFMA16(afh[i], wfl[j], acc[i][j]);
        acc[i][j] = MFMA16(afl[i], wfh[j], acc[i][j]);
      }
    __syncthreads();
  }
  const int cr = (lane >> 4) * 4;
  const int cc = lane & 15;
  #pragma unroll
  for (int i = 0; i < 4; ++i) {
    const int gm = m0 + (wm + i) * 16 + cr;
    #pragma unroll
    for (int j = 0; j < 4; ++j) {
      const int gc = n0 + (wn + j) * 16 + cc;
      #pragma unroll
      for (int r = 0; r < 4; ++r)
        C[(size_t)(gm + r) * DMOD + gc] =
            acc[i][j][r] + res[(size_t)(gm + r) * DMOD + gc];
    }
  }
}

// ---------------- MFMA attention per (bh, q-tile of 64) -------------------------
// Phase i computes S^T (A=K, B=Q) so P lands in LDS A-frag order via half4 writes.
// Phase ii computes O^T (A=Vt, B=P). All matmuls split-fp16 (hh+hl+lh).
// Grid (bh=128, qtile=8): bh%8 pins all q-tiles of one bh to one XCD (L2 reuse).
__global__ __launch_bounds__(256, 2) void k_attn(
    const _Float16* __restrict__ qh, const _Float16* __restrict__ ql,
    const _Float16* __restrict__ kh, const _Float16* __restrict__ kl,
    const _Float16* __restrict__ vth, const _Float16* __restrict__ vtl,
    const unsigned int* __restrict__ pk,
    _Float16* __restrict__ oh, _Float16* __restrict__ ol) {
  const int bh = blockIdx.x;
  const int q0 = blockIdx.y * 64;
  const size_t bhoff = (size_t)bh * 32768;
  __shared__ half8 Qh_s[512], Ql_s[512], Kh_s[512], Kl_s[512];
  __shared__ half8 Vh_s[512], Vl_s[512], Ph_s[512], Pl_s[512];
  __shared__ unsigned int Ms[64][2];
  __shared__ float Ps[4][64];
  __shared__ float lsum[64];
  const int tid = threadIdx.x;
  const int w = tid >> 6;          // wave id = k-row-subtile (i) / d-subtile (ii)
  const int lane = tid & 63;
  const int l15 = lane & 15;
  const int quad = lane >> 4;
  // stage Q tile in frag order: fi = (row>>4)*128 + kg*16 + (row&15)
  #pragma unroll
  for (int p = 0; p < 2; ++p) {
    const int lin = tid + p * 256;
    const int r = lin >> 3, g = lin & 7;
    const int fi = (r >> 4) * 128 + g * 16 + (r & 15);
    const size_t ga = bhoff + (size_t)(q0 + r) * 64 + g * 8;
    Qh_s[fi] = *(const half8*)(qh + ga);
    Ql_s[fi] = *(const half8*)(ql + ga);
  }
  float4v oacc[4];
  float lsw[4] = {0.f, 0.f, 0.f, 0.f};
  #pragma unroll
  for (int ns = 0; ns < 4; ++ns) oacc[ns] = (float4v){0.f, 0.f, 0.f, 0.f};
  __syncthreads();
  for (int kc = 0; kc < SLEN; kc += 64) {
    // stage K chunk (row-major) and Vt chunk ([d][s] rows) in frag order
    #pragma unroll
    for (int p = 0; p < 2; ++p) {
      const int lin = tid + p * 256;
      const int r = lin >> 3, g = lin & 7;
      const int fi = (r >> 4) * 128 + g * 16 + (r & 15);
      const size_t gk = bhoff + (size_t)(kc + r) * 64 + g * 8;
      const size_t gv = bhoff + (size_t)r * 512 + kc + g * 8;
      Kh_s[fi] = *(const half8*)(kh + gk);
      Kl_s[fi] = *(const half8*)(kl + gk);
      Vh_s[fi] = *(const half8*)(vth + gv);
      Vl_s[fi] = *(const half8*)(vtl + gv);
    }
    if (tid < 128)
      Ms[tid >> 1][tid & 1] =
          pk[((size_t)((bh >> 2) << 9) + q0 + (tid >> 1)) * 16 + (kc >> 5) + (tid & 1)];
    __syncthreads();
    // ---- phase i: S^T tile, rows k' = w*16.., cols q ----
    const int abase = w * 128 + quad * 16 + l15;
    const half8 ah0 = Kh_s[abase], ah1 = Kh_s[abase + 64];
    const half8 al0 = Kl_s[abase], al1 = Kl_s[abase + 64];
    #pragma unroll
    for (int ns = 0; ns < 4; ++ns) {
      const int bbase = ns * 128 + quad * 16 + l15;
      const half8 bh0 = Qh_s[bbase], bh1 = Qh_s[bbase + 64];
      const half8 bl0 = Ql_s[bbase], bl1 = Ql_s[bbase + 64];
      float4v s = (float4v){0.f, 0.f, 0.f, 0.f};
      s = MFMA16(ah0, bh0, s); s = MFMA16(ah1, bh1, s);
      s = MFMA16(ah0, bl0, s); s = MFMA16(ah1, bl1, s);
      s = MFMA16(al0, bh0, s); s = MFMA16(al1, bh1, s);
      const int q = ns * 16 + l15;
      const unsigned long long mrow = *(const unsigned long long*)&Ms[q][0];
      const unsigned mbits = (unsigned)(mrow >> (w * 16 + quad * 4)) & 15u;
      float pv[4]; float ps = 0.f;
      #pragma unroll
      for (int r = 0; r < 4; ++r) {
        const float e = s[r] * 0.125f;
        const float pe = ((mbits >> r) & 1u) ? __expf(e) : 0.f;
        pv[r] = pe; ps += pe;
      }
      half4 h4, l4;
      #pragma unroll
      for (int r = 0; r < 4; ++r) {
        h4[r] = (_Float16)pv[r];
        l4[r] = (_Float16)(pv[r] - (float)h4[r]);
      }
      // P element (q,k'): fi = ns*128 + (k'>>3)*16 + l15, j = k'&7; regs contiguous
      const int hb = ((ns * 8 + w * 2 + (quad >> 1)) * 16 + l15) * 8 + (quad & 1) * 4;
      *(half4*)((_Float16*)Ph_s + hb) = h4;
      *(half4*)((_Float16*)Pl_s + hb) = l4;
      ps += __shfl_xor(ps, 16);
      ps += __shfl_xor(ps, 32);
      lsw[ns] += ps;
    }
    __syncthreads();
    // ---- phase ii: O^T += Vt-chunk x P, rows d = w*16.., cols q ----
    const half8 vh0 = Vh_s[abase], vh1 = Vh_s[abase + 64];
    const half8 vl0 = Vl_s[abase], vl1 = Vl_s[abase + 64];
    #pragma unroll
    for (int ns = 0; ns < 4; ++ns) {
      const int pb = ns * 128 + quad * 16 + l15;
      const half8 ph0 = Ph_s[pb], ph1 = Ph_s[pb + 64];
      const half8 pl0 = Pl_s[pb], pl1 = Pl_s[pb + 64];
      oacc[ns] = MFMA16(vh0, ph0, oacc[ns]); oacc[ns] = MFMA16(vh1, ph1, oacc[ns]);
      oacc[ns] = MFMA16(vh0, pl0, oacc[ns]); oacc[ns] = MFMA16(vh1, pl1, oacc[ns]);
      oacc[ns] = MFMA16(vl0, ph0, oacc[ns]); oacc[ns] = MFMA16(vl1, ph1, oacc[ns]);
    }
    __syncthreads();
  }
  // row-sum reduce across waves
  if (quad == 0) {
    #pragma unroll
    for (int ns = 0; ns < 4; ++ns) Ps[w][ns * 16 + l15] = lsw[ns];
  }
  __syncthreads();
  if (tid < 64) lsum[tid] = Ps[0][tid] + Ps[1][tid] + Ps[2][tid] + Ps[3][tid];
  __syncthreads();
  // epilogue: lane holds (d = w*16 + quad*4 + r, q = ns*16 + l15)
  const int b = bh >> 2, h = bh & 3;
  #pragma unroll
  for (int ns = 0; ns < 4; ++ns) {
    const int q = ns * 16 + l15;
    const float inv = 1.0f / lsum[q];
    const size_t base =
        ((size_t)(b * SLEN + q0 + q)) * DMOD + h * HDIM + w * 16 + quad * 4;
    half4 h4, l4;
    #pragma unroll
    for (int r = 0; r < 4; ++r) {
      const float v = oacc[ns][r] * inv;
      h4[r] = (_Float16)v;
      l4[r] = (_Float16)(v - (float)h4[r]);
    }
    *(half4*)(oh + base) = h4;
    *(half4*)(ol + base) = l4;
  }
}

// ---------------- layer norm + zero invalid rows ----------------
__global__ __launch_bounds__(256) void k_ln(
    const float* __restrict__ Y, const int* __restrict__ lengths,
    const float* __restrict__ g, const float* __restrict__ bb,
    float* __restrict__ out) {
  const int row = blockIdx.x * 4 + (threadIdx.x >> 6);
  const int lane = threadIdx.x & 63;
  const int b = row >> 9, s = row & 511;
  const float* yr = Y + (size_t)row * DMOD;
  float v[4];
  *(float4*)v = *(const float4*)(yr + lane * 4);
  float sum = v[0] + v[1] + v[2] + v[3];
  #pragma unroll
  for (int off = 32; off > 0; off >>= 1) sum += __shfl_xor(sum, off);
  const float mu = sum * (1.0f / DMOD);
  float vs = 0.f;
  #pragma unroll
  for (int i = 0; i < 4; ++i) { const float dx = v[i] - mu; vs += dx * dx; }
  #pragma unroll
  for (int off = 32; off > 0; off >>= 1) vs += __shfl_xor(vs, off);
  const float inv = rsqrtf(vs * (1.0f / DMOD) + 1e-5f);
  const bool valid = s < lengths[b];
  float gg[4], bv[4], ov[4];
  *(float4*)gg = *(const float4*)(g + lane * 4);
  *(float4*)bv = *(const float4*)(bb + lane * 4);
  #pragma unroll
  for (int i = 0; i < 4; ++i)
    ov[i] = valid ? ((v[i] - mu) * inv * gg[i] + bv[i]) : 0.f;
  *(float4*)(out + (size_t)row * DMOD + lane * 4) = *(float4*)ov;
}

// ---------------- triangular temporal pooling, 4 bins fused, s-chunked ----------
__global__ __launch_bounds__(256) void k_pool(
    const float* __restrict__ X, const int* __restrict__ lengths,
    float* __restrict__ Up) {
  const int b = blockIdx.x;
  const int c = blockIdx.y;
  const int d = threadIdx.x;
  const float inv4 = 4.0f / (float)lengths[b];
  float a0 = 0.f, a1 = 0.f, a2 = 0.f, a3 = 0.f;
  for (int s = c * 128; s < c * 128 + 128; ++s) {
    const float sv = (float)(s + 1) * inv4;
    const float xv = X[((size_t)b * SLEN + s) * DMOD + d];
    float t;
    t = 1.0f - fabsf(sv - 1.0f) * 0.25f; a0 += t * t * xv;
    t = 1.0f - fabsf(sv - 2.0f) * 0.25f; a1 += t * t * xv;
    t = 1.0f - fabsf(sv - 3.0f) * 0.25f; a2 += t * t * xv;
    t = 1.0f - fabsf(sv - 4.0f) * 0.25f; a3 += t * t * xv;
  }
  float* up = Up + (((size_t)b * 4 + c) * 4) * DMOD + d;
  up[0 * DMOD] = a0; up[1 * DMOD] = a1; up[2 * DMOD] = a2; up[3 * DMOD] = a3;
}

// ---------------- final [32,1024] @ [1024,2]^T + bias ---------------------------
__global__ __launch_bounds__(256) void k_out(
    const float* __restrict__ Up, const float* __restrict__ ow,
    const float* __restrict__ ob, float* __restrict__ out) {
  const int tid = threadIdx.x;
  const int pair = tid >> 2;
  const int part = tid & 3;
  const int b = pair >> 1, i = pair & 1;
  const float* upb = Up + ((size_t)b * 16 + part) * DMOD;
  const float* wb = ow + (size_t)i * 1024 + part * DMOD;
  float acc = 0.f;
  for (int d = 0; d < DMOD; d += 4) {
    const float4 u0 = *(const float4*)(upb + d);
    const float4 u1 = *(const float4*)(upb + 4 * DMOD + d);
    const float4 u2 = *(const float4*)(upb + 8 * DMOD + d);
    const float4 u3 = *(const float4*)(upb + 12 * DMOD + d);
    const float4 w = *(const float4*)(wb + d);
    acc += (u0.x + u1.x + u2.x + u3.x) * w.x + (u0.y + u1.y + u2.y + u3.y) * w.y +
           (u0.z + u1.z + u2.z + u3.z) * w.z + (u0.w + u1.w + u2.w + u3.w) * w.w;
  }
  acc += __shfl_xor(acc, 1);
  acc += __shfl_xor(acc, 2);
  if (part == 0) out[b * 2 + i] = acc + ob[i];
}

extern "C" void kernel_launch(void* const* d_in, const int* in_sizes, int n_in,
                              void* d_out, int out_size, void* d_ws, size_t ws_size,
                              hipStream_t stream) {
  const int* seqs     = (const int*)d_in[0];
  const int* masks    = (const int*)d_in[1];
  const int* lengths  = (const int*)d_in[2];
  const float* emb    = (const float*)d_in[5];
  const float* bias   = (const float*)d_in[6];
  const float* pe     = (const float*)d_in[7];
  const float* Wq     = (const float*)d_in[8];
  const float* Wk     = (const float*)d_in[9];
  const float* Wv     = (const float*)d_in[10];
  const float* Wfc    = (const float*)d_in[11];
  const float* ln_g   = (const float*)d_in[12];
  const float* ln_b   = (const float*)d_in[13];
  const float* out_w  = (const float*)d_in[14];
  const float* out_b  = (const float*)d_in[15];
  float* outp = (float*)d_out;

  float* ws = (float*)d_ws;
  const size_t NE = (size_t)BSZ * SLEN * DMOD;   // 4,194,304
  float* x = ws;                                 // fp32 residual
  _Float16* qh = (_Float16*)(x + NE);
  _Float16* ql = qh + NE;
  _Float16* kh = ql + NE;
  _Float16* kl = kh + NE;
  _Float16* vth = kl + NE;
  _Float16* vtl = vth + NE;
  _Float16* xh = vtl + NE;
  _Float16* xl = xh + NE;
  _Float16* oh = xl + NE;
  _Float16* ol = oh + NE;
  _Float16* wh = ol + NE;                        // 4*65536 halfs
  _Float16* wl = wh + 4 * 65536;
  unsigned int* pk = (unsigned int*)(wl + 4 * 65536);
  float* Up = (float*)(pk + BSZ * SLEN * 16);
  float* y = (float*)qh;                         // alias: qh/ql dead after attn

  k_embed<<<BSZ * SLEN / 4, 256, 0, stream>>>(seqs, lengths, emb, bias, pe, x, xh, xl);
  k_wsplit<<<dim3(32, 4), 256, 0, stream>>>(Wq, Wk, Wv, Wfc, wh, wl);
  k_maskpack<<<BSZ * SLEN, 256, 0, stream>>>(masks, pk);
  k_gemm_qkv<<<dim3(128, 2, 3), 256, 0, stream>>>(
      xh, xl, wh, wl, qh, ql, kh, kl, vth, vtl);
  k_attn<<<dim3(BSZ * NH, SLEN / 64), 256, 0, stream>>>(
      qh, ql, kh, kl, vth, vtl, pk, oh, ol);
  k_gemm_fc<<<dim3(128, 2), 256, 0, stream>>>(
      oh, ol, wh + 3 * 65536, wl + 3 * 65536, y, x);
  k_ln<<<BSZ * SLEN / 4, 256, 0, stream>>>(y, lengths, ln_g, ln_b, y);
  k_pool<<<dim3(BSZ, 4), 256, 0, stream>>>(y, lengths, Up);
  k_out<<<1, 256, 0, stream>>>(Up, out_w, out_b, outp);
}

// Round 7
// 359.781 us; speedup vs baseline: 3.8426x; 1.0335x over previous
//
#include <hip/hip_runtime.h>

#define BSZ 32
#define SLEN 512
#define CLEN 20
#define DMOD 256
#define NH 4
#define HDIM 64

typedef _Float16 half8 __attribute__((ext_vector_type(8)));
typedef _Float16 half4 __attribute__((ext_vector_type(4)));
typedef float float4v __attribute__((ext_vector_type(4)));

#define MFMA16(a, b, c) __builtin_amdgcn_mfma_f32_16x16x32_f16(a, b, c, 0, 0, 0)

// ---------------- embedding sum + positional encoding -> fp16 hi/lo ------------
__global__ __launch_bounds__(256) void k_embed(
    const int* __restrict__ seqs, const int* __restrict__ lengths,
    const float* __restrict__ emb, const float* __restrict__ bias,
    const float* __restrict__ pe,
    _Float16* __restrict__ xh, _Float16* __restrict__ xl) {
  const int row0 = blockIdx.x * 4;
  const int sub = threadIdx.x >> 6;
  const int lane = threadIdx.x & 63;
  const int row = row0 + sub;
  const int b = row >> 9, s = row & 511;
  __shared__ int codes[4][CLEN];
  if (threadIdx.x < 4 * CLEN)
    codes[threadIdx.x / CLEN][threadIdx.x % CLEN] = seqs[row0 * CLEN + threadIdx.x];
  __syncthreads();
  const int pos = (s < lengths[b]) ? (s + 1) : 0;
  const int d = lane * 4;
  float4 acc = *(const float4*)(bias + d);
  const float4 pv = *(const float4*)(pe + (size_t)pos * DMOD + d);
  acc.x += pv.x; acc.y += pv.y; acc.z += pv.z; acc.w += pv.w;
  #pragma unroll
  for (int c = 0; c < CLEN; ++c) {
    const float4 ev = *(const float4*)(emb + (size_t)codes[sub][c] * DMOD + d);
    acc.x += ev.x; acc.y += ev.y; acc.z += ev.z; acc.w += ev.w;
  }
  const size_t off = (size_t)row * DMOD + d;
  float a[4] = {acc.x, acc.y, acc.z, acc.w};
  half4 hv, lv;
  #pragma unroll
  for (int i = 0; i < 4; ++i) {
    hv[i] = (_Float16)a[i];
    lv[i] = (_Float16)(a[i] - (float)hv[i]);
  }
  *(half4*)(xh + off) = hv;
  *(half4*)(xl + off) = lv;
}

// ---------------- split 4 weight matrices [256x256] fp32 -> fp16 hi/lo ---------
__global__ __launch_bounds__(256) void k_wsplit(
    const float* __restrict__ W0, const float* __restrict__ W1,
    const float* __restrict__ W2, const float* __restrict__ W3,
    _Float16* __restrict__ wh, _Float16* __restrict__ wl) {
  const int z = blockIdx.y;
  const float* W = (z == 0) ? W0 : (z == 1) ? W1 : (z == 2) ? W2 : W3;
  const int idx = (blockIdx.x * 256 + threadIdx.x) * 8;
  float v[8];
  *(float4*)v = *(const float4*)(W + idx);
  *(float4*)(v + 4) = *(const float4*)(W + idx + 4);
  half8 h, l;
  #pragma unroll
  for (int i = 0; i < 8; ++i) {
    h[i] = (_Float16)v[i];
    l[i] = (_Float16)(v[i] - (float)h[i]);
  }
  *(half8*)(wh + (size_t)z * 65536 + idx) = h;
  *(half8*)(wl + (size_t)z * 65536 + idx) = l;
}

// ---------------- bit-pack attention mask: [32,512,512] int -> [32,512,16] u32 ----
__global__ __launch_bounds__(256) void k_maskpack(
    const int* __restrict__ masks, unsigned int* __restrict__ pk) {
  const int bq = blockIdx.x;
  const int wv = threadIdx.x >> 6;
  const int lane = threadIdx.x & 63;
  #pragma unroll
  for (int p = 0; p < 2; ++p) {
    const int chunk = wv + p * 4;
    const int m = masks[(size_t)bq * SLEN + chunk * 64 + lane];
    const unsigned long long bal = __ballot(m != 0);
    if (lane == 0) {
      pk[(size_t)bq * 16 + chunk * 2]     = (unsigned int)bal;
      pk[(size_t)bq * 16 + chunk * 2 + 1] = (unsigned int)(bal >> 32);
    }
  }
}

// ---------------- QKV GEMM via split-fp16 MFMA; row-major hi/lo outputs ---------
__global__ __launch_bounds__(256) void k_gemm_qkv(
    const _Float16* __restrict__ Ah, const _Float16* __restrict__ Al,
    const _Float16* __restrict__ Whb, const _Float16* __restrict__ Wlb,
    _Float16* __restrict__ qh, _Float16* __restrict__ ql,
    _Float16* __restrict__ kh, _Float16* __restrict__ kl,
    _Float16* __restrict__ vh, _Float16* __restrict__ vl) {
  const int z = blockIdx.z;
  _Float16* hB = (z == 0) ? qh : (z == 1) ? kh : vh;
  _Float16* lB = (z == 0) ? ql : (z == 1) ? kl : vl;
  const _Float16* wh = Whb + (size_t)z * 65536;
  const _Float16* wl = Wlb + (size_t)z * 65536;
  const int m0 = blockIdx.x * 128;
  const int n0 = blockIdx.y * 128;
  const int tid = threadIdx.x;
  const int lane = tid & 63;
  const int w = tid >> 6;
  const int wm = (w >> 1) * 4;
  const int wn = (w & 1) * 4;
  __shared__ half8 As_h[512], As_l[512], Ws_h[512], Ws_l[512];
  float4v acc[4][4];
  #pragma unroll
  for (int i = 0; i < 4; ++i)
    #pragma unroll
    for (int j = 0; j < 4; ++j)
      acc[i][j] = (float4v){0.f, 0.f, 0.f, 0.f};
  for (int k0 = 0; k0 < DMOD; k0 += 32) {
    #pragma unroll
    for (int p = 0; p < 2; ++p) {
      const int c = tid + p * 256;
      const int r = c & 127, qd = c >> 7;
      const int li = (r >> 4) * 64 + qd * 16 + (r & 15);
      const size_t ga = (size_t)(m0 + r) * DMOD + k0 + qd * 8;
      const size_t gw = (size_t)(n0 + r) * DMOD + k0 + qd * 8;
      As_h[li] = *(const half8*)(Ah + ga);
      As_l[li] = *(const half8*)(Al + ga);
      Ws_h[li] = *(const half8*)(wh + gw);
      Ws_l[li] = *(const half8*)(wl + gw);
    }
    __syncthreads();
    half8 afh[4], afl[4], wfh[4], wfl[4];
    #pragma unroll
    for (int i = 0; i < 4; ++i) {
      afh[i] = As_h[(wm + i) * 64 + lane];
      afl[i] = As_l[(wm + i) * 64 + lane];
      wfh[i] = Ws_h[(wn + i) * 64 + lane];
      wfl[i] = Ws_l[(wn + i) * 64 + lane];
    }
    #pragma unroll
    for (int i = 0; i < 4; ++i)
      #pragma unroll
      for (int j = 0; j < 4; ++j) {
        acc[i][j] = MFMA16(afh[i], wfh[j], acc[i][j]);
        acc[i][j] = MFMA16(afh[i], wfl[j], acc[i][j]);
        acc[i][j] = MFMA16(afl[i], wfh[j], acc[i][j]);
      }
    __syncthreads();
  }
  const int cr = (lane >> 4) * 4;
  const int cc = lane & 15;
  #pragma unroll
  for (int i = 0; i < 4; ++i) {
    const int gm = m0 + (wm + i) * 16 + cr;
    #pragma unroll
    for (int j = 0; j < 4; ++j) {
      const int gc = n0 + (wn + j) * 16 + cc;
      #pragma unroll
      for (int r = 0; r < 4; ++r) {
        const float val = acc[i][j][r];
        const _Float16 h = (_Float16)val;
        const size_t flat = (size_t)(gm + r) * DMOD + gc;
        hB[flat] = h;
        lB[flat] = (_Float16)(val - (float)h);
      }
    }
  }
}

// ---------------- per-bh transpose: v[bh][s][d] -> vt[bh][d][s] -----------------
__global__ __launch_bounds__(256) void k_vt(
    const _Float16* __restrict__ vh, const _Float16* __restrict__ vl,
    _Float16* __restrict__ vth, _Float16* __restrict__ vtl) {
  const int bh = blockIdx.x;
  const size_t off = (size_t)bh * 32768;
  __shared__ _Float16 Th[64][66], Tl[64][66];
  const int tid = threadIdx.x;
  const int c0 = blockIdx.y * 4;
  for (int c = c0; c < c0 + 4; ++c) {
    const int sc = c * 64;
    #pragma unroll
    for (int p = 0; p < 2; ++p) {
      const int lin = tid + p * 256;
      const int r = lin >> 3, g = lin & 7;
      *(half8*)&Th[r][g * 8] = *(const half8*)(vh + off + (size_t)(sc + r) * 64 + g * 8);
      *(half8*)&Tl[r][g * 8] = *(const half8*)(vl + off + (size_t)(sc + r) * 64 + g * 8);
    }
    __syncthreads();
    #pragma unroll
    for (int p = 0; p < 2; ++p) {
      const int lin = tid + p * 256;
      const int d = lin >> 3, sg = lin & 7;
      half8 hv, lv;
      #pragma unroll
      for (int j = 0; j < 8; ++j) {
        hv[j] = Th[sg * 8 + j][d];
        lv[j] = Tl[sg * 8 + j][d];
      }
      *(half8*)(vth + off + (size_t)d * 512 + sc + sg * 8) = hv;
      *(half8*)(vtl + off + (size_t)d * 512 + sc + sg * 8) = lv;
    }
    __syncthreads();
  }
}

// ---------------- FC GEMM (fp32 out + hi/lo residual), split-fp16 MFMA ----------
__global__ __launch_bounds__(256) void k_gemm_fc(
    const _Float16* __restrict__ Ah, const _Float16* __restrict__ Al,
    const _Float16* __restrict__ wh, const _Float16* __restrict__ wl,
    float* __restrict__ C,
    const _Float16* __restrict__ resh, const _Float16* __restrict__ resl) {
  const int m0 = blockIdx.x * 128;
  const int n0 = blockIdx.y * 128;
  const int tid = threadIdx.x;
  const int lane = tid & 63;
  const int w = tid >> 6;
  const int wm = (w >> 1) * 4;
  const int wn = (w & 1) * 4;
  __shared__ half8 As_h[512], As_l[512], Ws_h[512], Ws_l[512];
  float4v acc[4][4];
  #pragma unroll
  for (int i = 0; i < 4; ++i)
    #pragma unroll
    for (int j = 0; j < 4; ++j)
      acc[i][j] = (float4v){0.f, 0.f, 0.f, 0.f};
  for (int k0 = 0; k0 < DMOD; k0 += 32) {
    #pragma unroll
    for (int p = 0; p < 2; ++p) {
      const int c = tid + p * 256;
      const int r = c & 127, qd = c >> 7;
      const int li = (r >> 4) * 64 + qd * 16 + (r & 15);
      const size_t ga = (size_t)(m0 + r) * DMOD + k0 + qd * 8;
      const size_t gw = (size_t)(n0 + r) * DMOD + k0 + qd * 8;
      As_h[li] = *(const half8*)(Ah + ga);
      As_l[li] = *(const half8*)(Al + ga);
      Ws_h[li] = *(const half8*)(wh + gw);
      Ws_l[li] = *(const half8*)(wl + gw);
    }
    __syncthreads();
    half8 afh[4], afl[4], wfh[4], wfl[4];
    #pragma unroll
    for (int i = 0; i < 4; ++i) {
      afh[i] = As_h[(wm + i) * 64 + lane];
      afl[i] = As_l[(wm + i) * 64 + lane];
      wfh[i] = Ws_h[(wn + i) * 64 + lane];
      wfl[i] = Ws_l[(wn + i) * 64 + lane];
    }
    #pragma unroll
    for (int i = 0; i < 4; ++i)
      #pragma unroll
      for (int j = 0; j < 4; ++j) {
        acc[i][j] = MFMA16(afh[i], wfh[j], acc[i][j]);
        acc[i][j] = MFMA16(afh[i], wfl[j], acc[i][j]);
        acc[i][j] = MFMA16(afl[i], wfh[j], acc[i][j]);
      }
    __syncthreads();
  }
  const int cr = (lane >> 4) * 4;
  const int cc = lane & 15;
  #pragma unroll
  for (int i = 0; i < 4; ++i) {
    const int gm = m0 + (wm + i) * 16 + cr;
    #pragma unroll
    for (int j = 0; j < 4; ++j) {
      const int gc = n0 + (wn + j) * 16 + cc;
      #pragma unroll
      for (int r = 0; r < 4; ++r) {
        const size_t flat = (size_t)(gm + r) * DMOD + gc;
        C[flat] = acc[i][j][r] + (float)resh[flat] + (float)resl[flat];
      }
    }
  }
}

// ---------------- MFMA attention per (bh, q-tile of 64) -------------------------
// Phase i computes S^T (A=K, B=Q) so P lands in LDS A-frag order via half4 writes.
// Phase ii computes O^T (A=Vt, B=P). All matmuls split-fp16 (hh+hl+lh).
__global__ __launch_bounds__(256, 2) void k_attn(
    const _Float16* __restrict__ qh, const _Float16* __restrict__ ql,
    const _Float16* __restrict__ kh, const _Float16* __restrict__ kl,
    const _Float16* __restrict__ vth, const _Float16* __restrict__ vtl,
    const unsigned int* __restrict__ pk,
    _Float16* __restrict__ oh, _Float16* __restrict__ ol) {
  const int bh = blockIdx.x;
  const int q0 = blockIdx.y * 64;
  const size_t bhoff = (size_t)bh * 32768;
  __shared__ half8 Qh_s[512], Ql_s[512], Kh_s[512], Kl_s[512];
  __shared__ half8 Vh_s[512], Vl_s[512], Ph_s[512], Pl_s[512];
  __shared__ unsigned int Ms[64][2];
  __shared__ float Ps[4][64];
  __shared__ float lsum[64];
  const int tid = threadIdx.x;
  const int w = tid >> 6;
  const int lane = tid & 63;
  const int l15 = lane & 15;
  const int quad = lane >> 4;
  #pragma unroll
  for (int p = 0; p < 2; ++p) {
    const int lin = tid + p * 256;
    const int r = lin >> 3, g = lin & 7;
    const int fi = (r >> 4) * 128 + g * 16 + (r & 15);
    const size_t ga = bhoff + (size_t)(q0 + r) * 64 + g * 8;
    Qh_s[fi] = *(const half8*)(qh + ga);
    Ql_s[fi] = *(const half8*)(ql + ga);
  }
  float4v oacc[4];
  float lsw[4] = {0.f, 0.f, 0.f, 0.f};
  #pragma unroll
  for (int ns = 0; ns < 4; ++ns) oacc[ns] = (float4v){0.f, 0.f, 0.f, 0.f};
  __syncthreads();
  for (int kc = 0; kc < SLEN; kc += 64) {
    #pragma unroll
    for (int p = 0; p < 2; ++p) {
      const int lin = tid + p * 256;
      const int r = lin >> 3, g = lin & 7;
      const int fi = (r >> 4) * 128 + g * 16 + (r & 15);
      const size_t gk = bhoff + (size_t)(kc + r) * 64 + g * 8;
      const size_t gv = bhoff + (size_t)r * 512 + kc + g * 8;
      Kh_s[fi] = *(const half8*)(kh + gk);
      Kl_s[fi] = *(const half8*)(kl + gk);
      Vh_s[fi] = *(const half8*)(vth + gv);
      Vl_s[fi] = *(const half8*)(vtl + gv);
    }
    if (tid < 128)
      Ms[tid >> 1][tid & 1] =
          pk[((size_t)((bh >> 2) << 9) + q0 + (tid >> 1)) * 16 + (kc >> 5) + (tid & 1)];
    __syncthreads();
    const int abase = w * 128 + quad * 16 + l15;
    const half8 ah0 = Kh_s[abase], ah1 = Kh_s[abase + 64];
    const half8 al0 = Kl_s[abase], al1 = Kl_s[abase + 64];
    #pragma unroll
    for (int ns = 0; ns < 4; ++ns) {
      const int bbase = ns * 128 + quad * 16 + l15;
      const half8 bh0 = Qh_s[bbase], bh1 = Qh_s[bbase + 64];
      const half8 bl0 = Ql_s[bbase], bl1 = Ql_s[bbase + 64];
      float4v s = (float4v){0.f, 0.f, 0.f, 0.f};
      s = MFMA16(ah0, bh0, s); s = MFMA16(ah1, bh1, s);
      s = MFMA16(ah0, bl0, s); s = MFMA16(ah1, bl1, s);
      s = MFMA16(al0, bh0, s); s = MFMA16(al1, bh1, s);
      const int q = ns * 16 + l15;
      const unsigned long long mrow = *(const unsigned long long*)&Ms[q][0];
      const unsigned mbits = (unsigned)(mrow >> (w * 16 + quad * 4)) & 15u;
      float pv[4]; float ps = 0.f;
      #pragma unroll
      for (int r = 0; r < 4; ++r) {
        const float e = s[r] * 0.125f;
        const float pe = ((mbits >> r) & 1u) ? __expf(e) : 0.f;
        pv[r] = pe; ps += pe;
      }
      half4 h4, l4;
      #pragma unroll
      for (int r = 0; r < 4; ++r) {
        h4[r] = (_Float16)pv[r];
        l4[r] = (_Float16)(pv[r] - (float)h4[r]);
      }
      const int hb = ((ns * 8 + w * 2 + (quad >> 1)) * 16 + l15) * 8 + (quad & 1) * 4;
      *(half4*)((_Float16*)Ph_s + hb) = h4;
      *(half4*)((_Float16*)Pl_s + hb) = l4;
      ps += __shfl_xor(ps, 16);
      ps += __shfl_xor(ps, 32);
      lsw[ns] += ps;
    }
    __syncthreads();
    const half8 vh0 = Vh_s[abase], vh1 = Vh_s[abase + 64];
    const half8 vl0 = Vl_s[abase], vl1 = Vl_s[abase + 64];
    #pragma unroll
    for (int ns = 0; ns < 4; ++ns) {
      const int pb = ns * 128 + quad * 16 + l15;
      const half8 ph0 = Ph_s[pb], ph1 = Ph_s[pb + 64];
      const half8 pl0 = Pl_s[pb], pl1 = Pl_s[pb + 64];
      oacc[ns] = MFMA16(vh0, ph0, oacc[ns]); oacc[ns] = MFMA16(vh1, ph1, oacc[ns]);
      oacc[ns] = MFMA16(vh0, pl0, oacc[ns]); oacc[ns] = MFMA16(vh1, pl1, oacc[ns]);
      oacc[ns] = MFMA16(vl0, ph0, oacc[ns]); oacc[ns] = MFMA16(vl1, ph1, oacc[ns]);
    }
    __syncthreads();
  }
  if (quad == 0) {
    #pragma unroll
    for (int ns = 0; ns < 4; ++ns) Ps[w][ns * 16 + l15] = lsw[ns];
  }
  __syncthreads();
  if (tid < 64) lsum[tid] = Ps[0][tid] + Ps[1][tid] + Ps[2][tid] + Ps[3][tid];
  __syncthreads();
  const int b = bh >> 2, h = bh & 3;
  #pragma unroll
  for (int ns = 0; ns < 4; ++ns) {
    const int q = ns * 16 + l15;
    const float inv = 1.0f / lsum[q];
    const size_t base =
        ((size_t)(b * SLEN + q0 + q)) * DMOD + h * HDIM + w * 16 + quad * 4;
    half4 h4, l4;
    #pragma unroll
    for (int r = 0; r < 4; ++r) {
      const float v = oacc[ns][r] * inv;
      h4[r] = (_Float16)v;
      l4[r] = (_Float16)(v - (float)h4[r]);
    }
    *(half4*)(oh + base) = h4;
    *(half4*)(ol + base) = l4;
  }
}

// ---------------- layer norm + zero invalid rows ----------------
__global__ __launch_bounds__(256) void k_ln(
    const float* __restrict__ Y, const int* __restrict__ lengths,
    const float* __restrict__ g, const float* __restrict__ bb,
    float* __restrict__ out) {
  const int row = blockIdx.x * 4 + (threadIdx.x >> 6);
  const int lane = threadIdx.x & 63;
  const int b = row >> 9, s = row & 511;
  const float* yr = Y + (size_t)row * DMOD;
  float v[4];
  *(float4*)v = *(const float4*)(yr + lane * 4);
  float sum = v[0] + v[1] + v[2] + v[3];
  #pragma unroll
  for (int off = 32; off > 0; off >>= 1) sum += __shfl_xor(sum, off);
  const float mu = sum * (1.0f / DMOD);
  float vs = 0.f;
  #pragma unroll
  for (int i = 0; i < 4; ++i) { const float dx = v[i] - mu; vs += dx * dx; }
  #pragma unroll
  for (int off = 32; off > 0; off >>= 1) vs += __shfl_xor(vs, off);
  const float inv = rsqrtf(vs * (1.0f / DMOD) + 1e-5f);
  const bool valid = s < lengths[b];
  float gg[4], bv[4], ov[4];
  *(float4*)gg = *(const float4*)(g + lane * 4);
  *(float4*)bv = *(const float4*)(bb + lane * 4);
  #pragma unroll
  for (int i = 0; i < 4; ++i)
    ov[i] = valid ? ((v[i] - mu) * inv * gg[i] + bv[i]) : 0.f;
  *(float4*)(out + (size_t)row * DMOD + lane * 4) = *(float4*)ov;
}

// ---------------- triangular temporal pooling, 4 bins fused, s-chunked ----------
__global__ __launch_bounds__(256) void k_pool(
    const float* __restrict__ X, const int* __restrict__ lengths,
    float* __restrict__ Up) {
  const int b = blockIdx.x;
  const int c = blockIdx.y;
  const int d = threadIdx.x;
  const float inv4 = 4.0f / (float)lengths[b];
  float a0 = 0.f, a1 = 0.f, a2 = 0.f, a3 = 0.f;
  for (int s = c * 128; s < c * 128 + 128; ++s) {
    const float sv = (float)(s + 1) * inv4;
    const float xv = X[((size_t)b * SLEN + s) * DMOD + d];
    float t;
    t = 1.0f - fabsf(sv - 1.0f) * 0.25f; a0 += t * t * xv;
    t = 1.0f - fabsf(sv - 2.0f) * 0.25f; a1 += t * t * xv;
    t = 1.0f - fabsf(sv - 3.0f) * 0.25f; a2 += t * t * xv;
    t = 1.0f - fabsf(sv - 4.0f) * 0.25f; a3 += t * t * xv;
  }
  float* up = Up + (((size_t)b * 4 + c) * 4) * DMOD + d;
  up[0 * DMOD] = a0; up[1 * DMOD] = a1; up[2 * DMOD] = a2; up[3 * DMOD] = a3;
}

// ---------------- final [32,1024] @ [1024,2]^T + bias ---------------------------
__global__ __launch_bounds__(256) void k_out(
    const float* __restrict__ Up, const float* __restrict__ ow,
    const float* __restrict__ ob, float* __restrict__ out) {
  const int tid = threadIdx.x;
  const int pair = tid >> 2;
  const int part = tid & 3;
  const int b = pair >> 1, i = pair & 1;
  const float* upb = Up + ((size_t)b * 16 + part) * DMOD;
  const float* wb = ow + (size_t)i * 1024 + part * DMOD;
  float acc = 0.f;
  for (int d = 0; d < DMOD; d += 4) {
    const float4 u0 = *(const float4*)(upb + d);
    const float4 u1 = *(const float4*)(upb + 4 * DMOD + d);
    const float4 u2 = *(const float4*)(upb + 8 * DMOD + d);
    const float4 u3 = *(const float4*)(upb + 12 * DMOD + d);
    const float4 w = *(const float4*)(wb + d);
    acc += (u0.x + u1.x + u2.x + u3.x) * w.x + (u0.y + u1.y + u2.y + u3.y) * w.y +
           (u0.z + u1.z + u2.z + u3.z) * w.z + (u0.w + u1.w + u2.w + u3.w) * w.w;
  }
  acc += __shfl_xor(acc, 1);
  acc += __shfl_xor(acc, 2);
  if (part == 0) out[b * 2 + i] = acc + ob[i];
}

extern "C" void kernel_launch(void* const* d_in, const int* in_sizes, int n_in,
                              void* d_out, int out_size, void* d_ws, size_t ws_size,
                              hipStream_t stream) {
  const int* seqs     = (const int*)d_in[0];
  const int* masks    = (const int*)d_in[1];
  const int* lengths  = (const int*)d_in[2];
  const float* emb    = (const float*)d_in[5];
  const float* bias   = (const float*)d_in[6];
  const float* pe     = (const float*)d_in[7];
  const float* Wq     = (const float*)d_in[8];
  const float* Wk     = (const float*)d_in[9];
  const float* Wv     = (const float*)d_in[10];
  const float* Wfc    = (const float*)d_in[11];
  const float* ln_g   = (const float*)d_in[12];
  const float* ln_b   = (const float*)d_in[13];
  const float* out_w  = (const float*)d_in[14];
  const float* out_b  = (const float*)d_in[15];
  float* outp = (float*)d_out;

  const size_t NE = (size_t)BSZ * SLEN * DMOD;   // 4,194,304
  _Float16* qh = (_Float16*)d_ws;
  _Float16* ql = qh + NE;
  _Float16* kh = ql + NE;
  _Float16* kl = kh + NE;
  _Float16* vh = kl + NE;
  _Float16* vl = vh + NE;
  _Float16* vth = vl + NE;
  _Float16* vtl = vth + NE;
  _Float16* xh = vtl + NE;
  _Float16* xl = xh + NE;
  _Float16* oh = xl + NE;
  _Float16* ol = oh + NE;
  _Float16* wh = ol + NE;                        // 4*65536 halfs
  _Float16* wl = wh + 4 * 65536;
  unsigned int* pk = (unsigned int*)(wl + 4 * 65536);
  float* Up = (float*)(pk + BSZ * SLEN * 16);
  float* y = (float*)qh;                         // alias: qh/ql dead after attn

  k_embed<<<BSZ * SLEN / 4, 256, 0, stream>>>(seqs, lengths, emb, bias, pe, xh, xl);
  k_wsplit<<<dim3(32, 4), 256, 0, stream>>>(Wq, Wk, Wv, Wfc, wh, wl);
  k_maskpack<<<BSZ * SLEN, 256, 0, stream>>>(masks, pk);
  k_gemm_qkv<<<dim3(128, 2, 3), 256, 0, stream>>>(
      xh, xl, wh, wl, qh, ql, kh, kl, vh, vl);
  k_vt<<<dim3(BSZ * NH, 2), 256, 0, stream>>>(vh, vl, vth, vtl);
  k_attn<<<dim3(BSZ * NH, SLEN / 64), 256, 0, stream>>>(
      qh, ql, kh, kl, vth, vtl, pk, oh, ol);
  k_gemm_fc<<<dim3(128, 2), 256, 0, stream>>>(
      oh, ol, wh + 3 * 65536, wl + 3 * 65536, y, xh, xl);
  k_ln<<<BSZ * SLEN / 4, 256, 0, stream>>>(y, lengths, ln_g, ln_b, y);
  k_pool<<<dim3(BSZ, 4), 256, 0, stream>>>(y, lengths, Up);
  k_out<<<1, 256, 0, stream>>>(Up, out_w, out_b, outp);
}

// Round 8
// 335.628 us; speedup vs baseline: 4.1191x; 1.0720x over previous
//
#include <hip/hip_runtime.h>

#define BSZ 32
#define SLEN 512
#define CLEN 20
#define DMOD 256
#define NH 4
#define HDIM 64

typedef _Float16 half8 __attribute__((ext_vector_type(8)));
typedef _Float16 half4 __attribute__((ext_vector_type(4)));
typedef float float4v __attribute__((ext_vector_type(4)));

#define MFMA16(a, b, c) __builtin_amdgcn_mfma_f32_16x16x32_f16(a, b, c, 0, 0, 0)
// padded half8 index: groups of 16 half8 get stride 17 (breaks 256B-stride conflicts)
#define PG(fi) ((((fi) >> 4) * 17) + ((fi) & 15))

// ---------------- embedding sum + positional encoding -> fp16 hi/lo ------------
__global__ __launch_bounds__(256) void k_embed(
    const int* __restrict__ seqs, const int* __restrict__ lengths,
    const float* __restrict__ emb, const float* __restrict__ bias,
    const float* __restrict__ pe,
    _Float16* __restrict__ xh, _Float16* __restrict__ xl) {
  const int row0 = blockIdx.x * 4;
  const int sub = threadIdx.x >> 6;
  const int lane = threadIdx.x & 63;
  const int row = row0 + sub;
  const int b = row >> 9, s = row & 511;
  __shared__ int codes[4][CLEN];
  if (threadIdx.x < 4 * CLEN)
    codes[threadIdx.x / CLEN][threadIdx.x % CLEN] = seqs[row0 * CLEN + threadIdx.x];
  __syncthreads();
  const int pos = (s < lengths[b]) ? (s + 1) : 0;
  const int d = lane * 4;
  float4 acc = *(const float4*)(bias + d);
  const float4 pv = *(const float4*)(pe + (size_t)pos * DMOD + d);
  acc.x += pv.x; acc.y += pv.y; acc.z += pv.z; acc.w += pv.w;
  #pragma unroll
  for (int c = 0; c < CLEN; ++c) {
    const float4 ev = *(const float4*)(emb + (size_t)codes[sub][c] * DMOD + d);
    acc.x += ev.x; acc.y += ev.y; acc.z += ev.z; acc.w += ev.w;
  }
  const size_t off = (size_t)row * DMOD + d;
  float a[4] = {acc.x, acc.y, acc.z, acc.w};
  half4 hv, lv;
  #pragma unroll
  for (int i = 0; i < 4; ++i) {
    hv[i] = (_Float16)a[i];
    lv[i] = (_Float16)(a[i] - (float)hv[i]);
  }
  *(half4*)(xh + off) = hv;
  *(half4*)(xl + off) = lv;
}

// ---------------- split 4 weight matrices [256x256] fp32 -> fp16 hi/lo ---------
__global__ __launch_bounds__(256) void k_wsplit(
    const float* __restrict__ W0, const float* __restrict__ W1,
    const float* __restrict__ W2, const float* __restrict__ W3,
    _Float16* __restrict__ wh, _Float16* __restrict__ wl) {
  const int z = blockIdx.y;
  const float* W = (z == 0) ? W0 : (z == 1) ? W1 : (z == 2) ? W2 : W3;
  const int idx = (blockIdx.x * 256 + threadIdx.x) * 8;
  float v[8];
  *(float4*)v = *(const float4*)(W + idx);
  *(float4*)(v + 4) = *(const float4*)(W + idx + 4);
  half8 h, l;
  #pragma unroll
  for (int i = 0; i < 8; ++i) {
    h[i] = (_Float16)v[i];
    l[i] = (_Float16)(v[i] - (float)h[i]);
  }
  *(half8*)(wh + (size_t)z * 65536 + idx) = h;
  *(half8*)(wl + (size_t)z * 65536 + idx) = l;
}

// ---------------- bit-pack attention mask: [32,512,512] int -> [32,512,16] u32 ----
__global__ __launch_bounds__(256) void k_maskpack(
    const int* __restrict__ masks, unsigned int* __restrict__ pk) {
  const int bq = blockIdx.x;
  const int wv = threadIdx.x >> 6;
  const int lane = threadIdx.x & 63;
  #pragma unroll
  for (int p = 0; p < 2; ++p) {
    const int chunk = wv + p * 4;
    const int m = masks[(size_t)bq * SLEN + chunk * 64 + lane];
    const unsigned long long bal = __ballot(m != 0);
    if (lane == 0) {
      pk[(size_t)bq * 16 + chunk * 2]     = (unsigned int)bal;
      pk[(size_t)bq * 16 + chunk * 2 + 1] = (unsigned int)(bal >> 32);
    }
  }
}

// ---------------- QKV GEMM via split-fp16 MFMA; row-major hi/lo outputs ---------
__global__ __launch_bounds__(256) void k_gemm_qkv(
    const _Float16* __restrict__ Ah, const _Float16* __restrict__ Al,
    const _Float16* __restrict__ Whb, const _Float16* __restrict__ Wlb,
    _Float16* __restrict__ qh, _Float16* __restrict__ ql,
    _Float16* __restrict__ kh, _Float16* __restrict__ kl,
    _Float16* __restrict__ vh, _Float16* __restrict__ vl) {
  const int z = blockIdx.z;
  _Float16* hB = (z == 0) ? qh : (z == 1) ? kh : vh;
  _Float16* lB = (z == 0) ? ql : (z == 1) ? kl : vl;
  const _Float16* wh = Whb + (size_t)z * 65536;
  const _Float16* wl = Wlb + (size_t)z * 65536;
  const int m0 = blockIdx.x * 128;
  const int n0 = blockIdx.y * 128;
  const int tid = threadIdx.x;
  const int lane = tid & 63;
  const int w = tid >> 6;
  const int wm = (w >> 1) * 4;
  const int wn = (w & 1) * 4;
  __shared__ half8 As_h[512], As_l[512], Ws_h[512], Ws_l[512];
  float4v acc[4][4];
  #pragma unroll
  for (int i = 0; i < 4; ++i)
    #pragma unroll
    for (int j = 0; j < 4; ++j)
      acc[i][j] = (float4v){0.f, 0.f, 0.f, 0.f};
  for (int k0 = 0; k0 < DMOD; k0 += 32) {
    #pragma unroll
    for (int p = 0; p < 2; ++p) {
      const int c = tid + p * 256;
      const int r = c & 127, qd = c >> 7;
      const int li = (r >> 4) * 64 + qd * 16 + (r & 15);
      const size_t ga = (size_t)(m0 + r) * DMOD + k0 + qd * 8;
      const size_t gw = (size_t)(n0 + r) * DMOD + k0 + qd * 8;
      As_h[li] = *(const half8*)(Ah + ga);
      As_l[li] = *(const half8*)(Al + ga);
      Ws_h[li] = *(const half8*)(wh + gw);
      Ws_l[li] = *(const half8*)(wl + gw);
    }
    __syncthreads();
    half8 afh[4], afl[4], wfh[4], wfl[4];
    #pragma unroll
    for (int i = 0; i < 4; ++i) {
      afh[i] = As_h[(wm + i) * 64 + lane];
      afl[i] = As_l[(wm + i) * 64 + lane];
      wfh[i] = Ws_h[(wn + i) * 64 + lane];
      wfl[i] = Ws_l[(wn + i) * 64 + lane];
    }
    #pragma unroll
    for (int i = 0; i < 4; ++i)
      #pragma unroll
      for (int j = 0; j < 4; ++j) {
        acc[i][j] = MFMA16(afh[i], wfh[j], acc[i][j]);
        acc[i][j] = MFMA16(afh[i], wfl[j], acc[i][j]);
        acc[i][j] = MFMA16(afl[i], wfh[j], acc[i][j]);
      }
    __syncthreads();
  }
  const int cr = (lane >> 4) * 4;
  const int cc = lane & 15;
  #pragma unroll
  for (int i = 0; i < 4; ++i) {
    const int gm = m0 + (wm + i) * 16 + cr;
    #pragma unroll
    for (int j = 0; j < 4; ++j) {
      const int gc = n0 + (wn + j) * 16 + cc;
      #pragma unroll
      for (int r = 0; r < 4; ++r) {
        const float val = acc[i][j][r];
        const _Float16 h = (_Float16)val;
        const size_t flat = (size_t)(gm + r) * DMOD + gc;
        hB[flat] = h;
        lB[flat] = (_Float16)(val - (float)h);
      }
    }
  }
}

// ---------------- per-bh transpose: v[bh][s][d] -> vt[bh][d][s] -----------------
__global__ __launch_bounds__(256) void k_vt(
    const _Float16* __restrict__ vh, const _Float16* __restrict__ vl,
    _Float16* __restrict__ vth, _Float16* __restrict__ vtl) {
  const int bh = blockIdx.x;
  const size_t off = (size_t)bh * 32768;
  __shared__ _Float16 Th[64][66], Tl[64][66];
  const int tid = threadIdx.x;
  const int c0 = blockIdx.y * 4;
  for (int c = c0; c < c0 + 4; ++c) {
    const int sc = c * 64;
    #pragma unroll
    for (int p = 0; p < 2; ++p) {
      const int lin = tid + p * 256;
      const int r = lin >> 3, g = lin & 7;
      *(half8*)&Th[r][g * 8] = *(const half8*)(vh + off + (size_t)(sc + r) * 64 + g * 8);
      *(half8*)&Tl[r][g * 8] = *(const half8*)(vl + off + (size_t)(sc + r) * 64 + g * 8);
    }
    __syncthreads();
    #pragma unroll
    for (int p = 0; p < 2; ++p) {
      const int lin = tid + p * 256;
      const int d = lin >> 3, sg = lin & 7;
      half8 hv, lv;
      #pragma unroll
      for (int j = 0; j < 8; ++j) {
        hv[j] = Th[sg * 8 + j][d];
        lv[j] = Tl[sg * 8 + j][d];
      }
      *(half8*)(vth + off + (size_t)d * 512 + sc + sg * 8) = hv;
      *(half8*)(vtl + off + (size_t)d * 512 + sc + sg * 8) = lv;
    }
    __syncthreads();
  }
}

// ---------------- FC GEMM (fp32 out + hi/lo residual), split-fp16 MFMA ----------
__global__ __launch_bounds__(256) void k_gemm_fc(
    const _Float16* __restrict__ Ah, const _Float16* __restrict__ Al,
    const _Float16* __restrict__ wh, const _Float16* __restrict__ wl,
    float* __restrict__ C,
    const _Float16* __restrict__ resh, const _Float16* __restrict__ resl) {
  const int m0 = blockIdx.x * 128;
  const int n0 = blockIdx.y * 128;
  const int tid = threadIdx.x;
  const int lane = tid & 63;
  const int w = tid >> 6;
  const int wm = (w >> 1) * 4;
  const int wn = (w & 1) * 4;
  __shared__ half8 As_h[512], As_l[512], Ws_h[512], Ws_l[512];
  float4v acc[4][4];
  #pragma unroll
  for (int i = 0; i < 4; ++i)
    #pragma unroll
    for (int j = 0; j < 4; ++j)
      acc[i][j] = (float4v){0.f, 0.f, 0.f, 0.f};
  for (int k0 = 0; k0 < DMOD; k0 += 32) {
    #pragma unroll
    for (int p = 0; p < 2; ++p) {
      const int c = tid + p * 256;
      const int r = c & 127, qd = c >> 7;
      const int li = (r >> 4) * 64 + qd * 16 + (r & 15);
      const size_t ga = (size_t)(m0 + r) * DMOD + k0 + qd * 8;
      const size_t gw = (size_t)(n0 + r) * DMOD + k0 + qd * 8;
      As_h[li] = *(const half8*)(Ah + ga);
      As_l[li] = *(const half8*)(Al + ga);
      Ws_h[li] = *(const half8*)(wh + gw);
      Ws_l[li] = *(const half8*)(wl + gw);
    }
    __syncthreads();
    half8 afh[4], afl[4], wfh[4], wfl[4];
    #pragma unroll
    for (int i = 0; i < 4; ++i) {
      afh[i] = As_h[(wm + i) * 64 + lane];
      afl[i] = As_l[(wm + i) * 64 + lane];
      wfh[i] = Ws_h[(wn + i) * 64 + lane];
      wfl[i] = Ws_l[(wn + i) * 64 + lane];
    }
    #pragma unroll
    for (int i = 0; i < 4; ++i)
      #pragma unroll
      for (int j = 0; j < 4; ++j) {
        acc[i][j] = MFMA16(afh[i], wfh[j], acc[i][j]);
        acc[i][j] = MFMA16(afh[i], wfl[j], acc[i][j]);
        acc[i][j] = MFMA16(afl[i], wfh[j], acc[i][j]);
      }
    __syncthreads();
  }
  const int cr = (lane >> 4) * 4;
  const int cc = lane & 15;
  #pragma unroll
  for (int i = 0; i < 4; ++i) {
    const int gm = m0 + (wm + i) * 16 + cr;
    #pragma unroll
    for (int j = 0; j < 4; ++j) {
      const int gc = n0 + (wn + j) * 16 + cc;
      #pragma unroll
      for (int r = 0; r < 4; ++r) {
        const size_t flat = (size_t)(gm + r) * DMOD + gc;
        C[flat] = acc[i][j][r] + (float)resh[flat] + (float)resl[flat];
      }
    }
  }
}

// ---------------- MFMA attention per (bh, q-tile of 64) -------------------------
// Padded frag-order LDS (group stride 17) -> conflict-free staging.
// Q frags hoisted to registers; Q LDS arrays reused for P. 3 blocks/CU.
__global__ __launch_bounds__(256, 3) void k_attn(
    const _Float16* __restrict__ qh, const _Float16* __restrict__ ql,
    const _Float16* __restrict__ kh, const _Float16* __restrict__ kl,
    const _Float16* __restrict__ vth, const _Float16* __restrict__ vtl,
    const unsigned int* __restrict__ pk,
    _Float16* __restrict__ oh, _Float16* __restrict__ ol) {
  const int bh = blockIdx.x;
  const int q0 = blockIdx.y * 64;
  const size_t bhoff = (size_t)bh * 32768;
  __shared__ half8 QPh[544], QPl[544];          // Q staging, then P
  __shared__ half8 Kh_s[544], Kl_s[544], Vh_s[544], Vl_s[544];
  __shared__ unsigned int Ms[64][2];
  __shared__ float Ps[4][64];
  __shared__ float lsum[64];
  const int tid = threadIdx.x;
  const int w = tid >> 6;
  const int lane = tid & 63;
  const int l15 = lane & 15;
  const int quad = lane >> 4;
  // stage Q in padded frag order
  #pragma unroll
  for (int p = 0; p < 2; ++p) {
    const int lin = tid + p * 256;
    const int r = lin >> 3, g = lin & 7;
    const int fi = (r >> 4) * 128 + g * 16 + (r & 15);
    const size_t ga = bhoff + (size_t)(q0 + r) * 64 + g * 8;
    QPh[PG(fi)] = *(const half8*)(qh + ga);
    QPl[PG(fi)] = *(const half8*)(ql + ga);
  }
  __syncthreads();
  // hoist Q fragments to registers (loop-invariant across kc)
  half8 qfh[4][2], qfl[4][2];
  #pragma unroll
  for (int ns = 0; ns < 4; ++ns) {
    const int gq = ns * 8 + quad;
    qfh[ns][0] = QPh[gq * 17 + l15];
    qfh[ns][1] = QPh[(gq + 4) * 17 + l15];
    qfl[ns][0] = QPl[gq * 17 + l15];
    qfl[ns][1] = QPl[(gq + 4) * 17 + l15];
  }
  float4v oacc[4];
  float lsw[4] = {0.f, 0.f, 0.f, 0.f};
  #pragma unroll
  for (int ns = 0; ns < 4; ++ns) oacc[ns] = (float4v){0.f, 0.f, 0.f, 0.f};
  for (int kc = 0; kc < SLEN; kc += 64) {
    __syncthreads();   // Q-frag reads (first iter) / prior phase-ii reads done
    #pragma unroll
    for (int p = 0; p < 2; ++p) {
      const int lin = tid + p * 256;
      const int r = lin >> 3, g = lin & 7;
      const int fi = PG((r >> 4) * 128 + g * 16 + (r & 15));
      const size_t gk = bhoff + (size_t)(kc + r) * 64 + g * 8;
      const size_t gv = bhoff + (size_t)r * 512 + kc + g * 8;
      Kh_s[fi] = *(const half8*)(kh + gk);
      Kl_s[fi] = *(const half8*)(kl + gk);
      Vh_s[fi] = *(const half8*)(vth + gv);
      Vl_s[fi] = *(const half8*)(vtl + gv);
    }
    if (tid < 128)
      Ms[tid >> 1][tid & 1] =
          pk[((size_t)((bh >> 2) << 9) + q0 + (tid >> 1)) * 16 + (kc >> 5) + (tid & 1)];
    __syncthreads();
    // ---- phase i: S^T subtiles; this wave owns k' rows [w*16, w*16+16) ----
    const int ga0 = (w * 8 + quad) * 17 + l15;
    const int ga1 = (w * 8 + quad + 4) * 17 + l15;
    const half8 ah0 = Kh_s[ga0], ah1 = Kh_s[ga1];
    const half8 al0 = Kl_s[ga0], al1 = Kl_s[ga1];
    #pragma unroll
    for (int ns = 0; ns < 4; ++ns) {
      float4v s = (float4v){0.f, 0.f, 0.f, 0.f};
      s = MFMA16(ah0, qfh[ns][0], s); s = MFMA16(ah1, qfh[ns][1], s);
      s = MFMA16(ah0, qfl[ns][0], s); s = MFMA16(ah1, qfl[ns][1], s);
      s = MFMA16(al0, qfh[ns][0], s); s = MFMA16(al1, qfh[ns][1], s);
      const int q = ns * 16 + l15;
      const unsigned long long mrow = *(const unsigned long long*)&Ms[q][0];
      const unsigned mbits = (unsigned)(mrow >> (w * 16 + quad * 4)) & 15u;
      float pv[4];
      #pragma unroll
      for (int r = 0; r < 4; ++r) {
        const float pe = ((mbits >> r) & 1u) ? __expf(s[r] * 0.125f) : 0.f;
        pv[r] = pe;
        lsw[ns] += pe;
      }
      half4 h4, l4;
      #pragma unroll
      for (int r = 0; r < 4; ++r) {
        h4[r] = (_Float16)pv[r];
        l4[r] = (_Float16)(pv[r] - (float)h4[r]);
      }
      const int hb = ((ns * 8 + w * 2 + (quad >> 1)) * 17 + l15) * 8 + (quad & 1) * 4;
      *(half4*)((_Float16*)QPh + hb) = h4;
      *(half4*)((_Float16*)QPl + hb) = l4;
    }
    __syncthreads();
    // ---- phase ii: O^T += Vt-chunk x P; this wave owns d rows [w*16, w*16+16) ----
    const half8 vh0 = Vh_s[ga0], vh1 = Vh_s[ga1];
    const half8 vl0 = Vl_s[ga0], vl1 = Vl_s[ga1];
    #pragma unroll
    for (int ns = 0; ns < 4; ++ns) {
      const int pb0 = (ns * 8 + quad) * 17 + l15;
      const int pb1 = (ns * 8 + quad + 4) * 17 + l15;
      const half8 ph0 = QPh[pb0], ph1 = QPh[pb1];
      const half8 pl0 = QPl[pb0], pl1 = QPl[pb1];
      oacc[ns] = MFMA16(vh0, ph0, oacc[ns]); oacc[ns] = MFMA16(vh1, ph1, oacc[ns]);
      oacc[ns] = MFMA16(vh0, pl0, oacc[ns]); oacc[ns] = MFMA16(vh1, pl1, oacc[ns]);
      oacc[ns] = MFMA16(vl0, ph0, oacc[ns]); oacc[ns] = MFMA16(vl1, ph1, oacc[ns]);
    }
  }
  // deferred cross-lane row-sum reduction, then cross-wave via LDS
  #pragma unroll
  for (int ns = 0; ns < 4; ++ns) {
    lsw[ns] += __shfl_xor(lsw[ns], 16);
    lsw[ns] += __shfl_xor(lsw[ns], 32);
  }
  __syncthreads();
  if (quad == 0) {
    #pragma unroll
    for (int ns = 0; ns < 4; ++ns) Ps[w][ns * 16 + l15] = lsw[ns];
  }
  __syncthreads();
  if (tid < 64) lsum[tid] = Ps[0][tid] + Ps[1][tid] + Ps[2][tid] + Ps[3][tid];
  __syncthreads();
  const int b = bh >> 2, h = bh & 3;
  #pragma unroll
  for (int ns = 0; ns < 4; ++ns) {
    const int q = ns * 16 + l15;
    const float inv = 1.0f / lsum[q];
    const size_t base =
        ((size_t)(b * SLEN + q0 + q)) * DMOD + h * HDIM + w * 16 + quad * 4;
    half4 h4, l4;
    #pragma unroll
    for (int r = 0; r < 4; ++r) {
      const float v = oacc[ns][r] * inv;
      h4[r] = (_Float16)v;
      l4[r] = (_Float16)(v - (float)h4[r]);
    }
    *(half4*)(oh + base) = h4;
    *(half4*)(ol + base) = l4;
  }
}

// ---------------- layer norm + zero invalid rows ----------------
__global__ __launch_bounds__(256) void k_ln(
    const float* __restrict__ Y, const int* __restrict__ lengths,
    const float* __restrict__ g, const float* __restrict__ bb,
    float* __restrict__ out) {
  const int row = blockIdx.x * 4 + (threadIdx.x >> 6);
  const int lane = threadIdx.x & 63;
  const int b = row >> 9, s = row & 511;
  const float* yr = Y + (size_t)row * DMOD;
  float v[4];
  *(float4*)v = *(const float4*)(yr + lane * 4);
  float sum = v[0] + v[1] + v[2] + v[3];
  #pragma unroll
  for (int off = 32; off > 0; off >>= 1) sum += __shfl_xor(sum, off);
  const float mu = sum * (1.0f / DMOD);
  float vs = 0.f;
  #pragma unroll
  for (int i = 0; i < 4; ++i) { const float dx = v[i] - mu; vs += dx * dx; }
  #pragma unroll
  for (int off = 32; off > 0; off >>= 1) vs += __shfl_xor(vs, off);
  const float inv = rsqrtf(vs * (1.0f / DMOD) + 1e-5f);
  const bool valid = s < lengths[b];
  float gg[4], bv[4], ov[4];
  *(float4*)gg = *(const float4*)(g + lane * 4);
  *(float4*)bv = *(const float4*)(bb + lane * 4);
  #pragma unroll
  for (int i = 0; i < 4; ++i)
    ov[i] = valid ? ((v[i] - mu) * inv * gg[i] + bv[i]) : 0.f;
  *(float4*)(out + (size_t)row * DMOD + lane * 4) = *(float4*)ov;
}

// ---------------- triangular temporal pooling, 4 bins fused, s-chunked ----------
__global__ __launch_bounds__(256) void k_pool(
    const float* __restrict__ X, const int* __restrict__ lengths,
    float* __restrict__ Up) {
  const int b = blockIdx.x;
  const int c = blockIdx.y;
  const int d = threadIdx.x;
  const float inv4 = 4.0f / (float)lengths[b];
  float a0 = 0.f, a1 = 0.f, a2 = 0.f, a3 = 0.f;
  for (int s = c * 128; s < c * 128 + 128; ++s) {
    const float sv = (float)(s + 1) * inv4;
    const float xv = X[((size_t)b * SLEN + s) * DMOD + d];
    float t;
    t = 1.0f - fabsf(sv - 1.0f) * 0.25f; a0 += t * t * xv;
    t = 1.0f - fabsf(sv - 2.0f) * 0.25f; a1 += t * t * xv;
    t = 1.0f - fabsf(sv - 3.0f) * 0.25f; a2 += t * t * xv;
    t = 1.0f - fabsf(sv - 4.0f) * 0.25f; a3 += t * t * xv;
  }
  float* up = Up + (((size_t)b * 4 + c) * 4) * DMOD + d;
  up[0 * DMOD] = a0; up[1 * DMOD] = a1; up[2 * DMOD] = a2; up[3 * DMOD] = a3;
}

// ---------------- final [32,1024] @ [1024,2]^T + bias ---------------------------
__global__ __launch_bounds__(256) void k_out(
    const float* __restrict__ Up, const float* __restrict__ ow,
    const float* __restrict__ ob, float* __restrict__ out) {
  const int tid = threadIdx.x;
  const int pair = tid >> 2;
  const int part = tid & 3;
  const int b = pair >> 1, i = pair & 1;
  const float* upb = Up + ((size_t)b * 16 + part) * DMOD;
  const float* wb = ow + (size_t)i * 1024 + part * DMOD;
  float acc = 0.f;
  for (int d = 0; d < DMOD; d += 4) {
    const float4 u0 = *(const float4*)(upb + d);
    const float4 u1 = *(const float4*)(upb + 4 * DMOD + d);
    const float4 u2 = *(const float4*)(upb + 8 * DMOD + d);
    const float4 u3 = *(const float4*)(upb + 12 * DMOD + d);
    const float4 w = *(const float4*)(wb + d);
    acc += (u0.x + u1.x + u2.x + u3.x) * w.x + (u0.y + u1.y + u2.y + u3.y) * w.y +
           (u0.z + u1.z + u2.z + u3.z) * w.z + (u0.w + u1.w + u2.w + u3.w) * w.w;
  }
  acc += __shfl_xor(acc, 1);
  acc += __shfl_xor(acc, 2);
  if (part == 0) out[b * 2 + i] = acc + ob[i];
}

extern "C" void kernel_launch(void* const* d_in, const int* in_sizes, int n_in,
                              void* d_out, int out_size, void* d_ws, size_t ws_size,
                              hipStream_t stream) {
  const int* seqs     = (const int*)d_in[0];
  const int* masks    = (const int*)d_in[1];
  const int* lengths  = (const int*)d_in[2];
  const float* emb    = (const float*)d_in[5];
  const float* bias   = (const float*)d_in[6];
  const float* pe     = (const float*)d_in[7];
  const float* Wq     = (const float*)d_in[8];
  const float* Wk     = (const float*)d_in[9];
  const float* Wv     = (const float*)d_in[10];
  const float* Wfc    = (const float*)d_in[11];
  const float* ln_g   = (const float*)d_in[12];
  const float* ln_b   = (const float*)d_in[13];
  const float* out_w  = (const float*)d_in[14];
  const float* out_b  = (const float*)d_in[15];
  float* outp = (float*)d_out;

  const size_t NE = (size_t)BSZ * SLEN * DMOD;   // 4,194,304
  _Float16* qh = (_Float16*)d_ws;
  _Float16* ql = qh + NE;
  _Float16* kh = ql + NE;
  _Float16* kl = kh + NE;
  _Float16* vh = kl + NE;
  _Float16* vl = vh + NE;
  _Float16* vth = vl + NE;
  _Float16* vtl = vth + NE;
  _Float16* xh = vtl + NE;
  _Float16* xl = xh + NE;
  _Float16* oh = xl + NE;
  _Float16* ol = oh + NE;
  _Float16* wh = ol + NE;                        // 4*65536 halfs
  _Float16* wl = wh + 4 * 65536;
  unsigned int* pk = (unsigned int*)(wl + 4 * 65536);
  float* Up = (float*)(pk + BSZ * SLEN * 16);
  float* y = (float*)qh;                         // alias: qh/ql dead after attn

  k_embed<<<BSZ * SLEN / 4, 256, 0, stream>>>(seqs, lengths, emb, bias, pe, xh, xl);
  k_wsplit<<<dim3(32, 4), 256, 0, stream>>>(Wq, Wk, Wv, Wfc, wh, wl);
  k_maskpack<<<BSZ * SLEN, 256, 0, stream>>>(masks, pk);
  k_gemm_qkv<<<dim3(128, 2, 3), 256, 0, stream>>>(
      xh, xl, wh, wl, qh, ql, kh, kl, vh, vl);
  k_vt<<<dim3(BSZ * NH, 2), 256, 0, stream>>>(vh, vl, vth, vtl);
  k_attn<<<dim3(BSZ * NH, SLEN / 64), 256, 0, stream>>>(
      qh, ql, kh, kl, vth, vtl, pk, oh, ol);
  k_gemm_fc<<<dim3(128, 2), 256, 0, stream>>>(
      oh, ol, wh + 3 * 65536, wl + 3 * 65536, y, xh, xl);
  k_ln<<<BSZ * SLEN / 4, 256, 0, stream>>>(y, lengths, ln_g, ln_b, y);
  k_pool<<<dim3(BSZ, 4), 256, 0, stream>>>(y, lengths, Up);
  k_out<<<1, 256, 0, stream>>>(Up, out_w, out_b, outp);
}

// Round 10
// 322.358 us; speedup vs baseline: 4.2887x; 1.0412x over previous
//
#include <hip/hip_runtime.h>

#define BSZ 32
#define SLEN 512
#define CLEN 20
#define DMOD 256
#define NH 4
#define HDIM 64

typedef _Float16 half8 __attribute__((ext_vector_type(8)));
typedef _Float16 half4 __attribute__((ext_vector_type(4)));
typedef float float4v __attribute__((ext_vector_type(4)));

#define MFMA16(a, b, c) __builtin_amdgcn_mfma_f32_16x16x32_f16(a, b, c, 0, 0, 0)
// padded half8 index: groups of 16 half8 get stride 17 (breaks 256B-stride conflicts)
#define PG(fi) ((((fi) >> 4) * 17) + ((fi) & 15))

// ---------------- embedding sum + positional encoding -> fp16 hi/lo ------------
__global__ __launch_bounds__(256) void k_embed(
    const int* __restrict__ seqs, const int* __restrict__ lengths,
    const float* __restrict__ emb, const float* __restrict__ bias,
    const float* __restrict__ pe,
    _Float16* __restrict__ xh, _Float16* __restrict__ xl) {
  const int row0 = blockIdx.x * 4;
  const int sub = threadIdx.x >> 6;
  const int lane = threadIdx.x & 63;
  const int row = row0 + sub;
  const int b = row >> 9, s = row & 511;
  __shared__ int codes[4][CLEN];
  if (threadIdx.x < 4 * CLEN)
    codes[threadIdx.x / CLEN][threadIdx.x % CLEN] = seqs[row0 * CLEN + threadIdx.x];
  __syncthreads();
  const int pos = (s < lengths[b]) ? (s + 1) : 0;
  const int d = lane * 4;
  float4 acc = *(const float4*)(bias + d);
  const float4 pv = *(const float4*)(pe + (size_t)pos * DMOD + d);
  acc.x += pv.x; acc.y += pv.y; acc.z += pv.z; acc.w += pv.w;
  #pragma unroll
  for (int c = 0; c < CLEN; ++c) {
    const float4 ev = *(const float4*)(emb + (size_t)codes[sub][c] * DMOD + d);
    acc.x += ev.x; acc.y += ev.y; acc.z += ev.z; acc.w += ev.w;
  }
  const size_t off = (size_t)row * DMOD + d;
  float a[4] = {acc.x, acc.y, acc.z, acc.w};
  half4 hv, lv;
  #pragma unroll
  for (int i = 0; i < 4; ++i) {
    hv[i] = (_Float16)a[i];
    lv[i] = (_Float16)(a[i] - (float)hv[i]);
  }
  *(half4*)(xh + off) = hv;
  *(half4*)(xl + off) = lv;
}

// ---------------- split 4 weight matrices [256x256] fp32 -> fp16 hi/lo ---------
__global__ __launch_bounds__(256) void k_wsplit(
    const float* __restrict__ W0, const float* __restrict__ W1,
    const float* __restrict__ W2, const float* __restrict__ W3,
    _Float16* __restrict__ wh, _Float16* __restrict__ wl) {
  const int z = blockIdx.y;
  const float* W = (z == 0) ? W0 : (z == 1) ? W1 : (z == 2) ? W2 : W3;
  const int idx = (blockIdx.x * 256 + threadIdx.x) * 8;
  float v[8];
  *(float4*)v = *(const float4*)(W + idx);
  *(float4*)(v + 4) = *(const float4*)(W + idx + 4);
  half8 h, l;
  #pragma unroll
  for (int i = 0; i < 8; ++i) {
    h[i] = (_Float16)v[i];
    l[i] = (_Float16)(v[i] - (float)h[i]);
  }
  *(half8*)(wh + (size_t)z * 65536 + idx) = h;
  *(half8*)(wl + (size_t)z * 65536 + idx) = l;
}

// ---------------- bit-pack attention mask: [32,512,512] int -> [32,512,16] u32 ----
__global__ __launch_bounds__(256) void k_maskpack(
    const int* __restrict__ masks, unsigned int* __restrict__ pk) {
  const int bq = blockIdx.x;
  const int wv = threadIdx.x >> 6;
  const int lane = threadIdx.x & 63;
  #pragma unroll
  for (int p = 0; p < 2; ++p) {
    const int chunk = wv + p * 4;
    const int m = masks[(size_t)bq * SLEN + chunk * 64 + lane];
    const unsigned long long bal = __ballot(m != 0);
    if (lane == 0) {
      pk[(size_t)bq * 16 + chunk * 2]     = (unsigned int)bal;
      pk[(size_t)bq * 16 + chunk * 2 + 1] = (unsigned int)(bal >> 32);
    }
  }
}

// ---------------- QKV GEMM: split-fp16 MFMA, prefetch, vectorized epilogue ------
// All outputs row-major hi/lo fp16 (v transposed separately by k_vt).
__global__ __launch_bounds__(256) void k_gemm_qkv(
    const _Float16* __restrict__ Ah, const _Float16* __restrict__ Al,
    const _Float16* __restrict__ Whb, const _Float16* __restrict__ Wlb,
    _Float16* __restrict__ qh, _Float16* __restrict__ ql,
    _Float16* __restrict__ kh, _Float16* __restrict__ kl,
    _Float16* __restrict__ vh, _Float16* __restrict__ vl) {
  const int z = blockIdx.z;
  _Float16* hB = (z == 0) ? qh : (z == 1) ? kh : vh;
  _Float16* lB = (z == 0) ? ql : (z == 1) ? kl : vl;
  const _Float16* wh = Whb + (size_t)z * 65536;
  const _Float16* wl = Wlb + (size_t)z * 65536;
  const int m0 = blockIdx.x * 128;
  const int n0 = blockIdx.y * 128;
  const int tid = threadIdx.x;
  const int lane = tid & 63;
  const int w = tid >> 6;
  const int wm = (w >> 1) * 4;
  const int wn = (w & 1) * 4;
  __shared__ _Float16 smem[16384];              // 32 KB, staging + epilogue reuse
  half8* As_h = (half8*)(smem);
  half8* As_l = (half8*)(smem + 4096);
  half8* Ws_h = (half8*)(smem + 8192);
  half8* Ws_l = (half8*)(smem + 12288);
  float4v acc[4][4];
  #pragma unroll
  for (int i = 0; i < 4; ++i)
    #pragma unroll
    for (int j = 0; j < 4; ++j)
      acc[i][j] = (float4v){0.f, 0.f, 0.f, 0.f};
  int li_[2]; size_t ga_[2], gw_[2];
  #pragma unroll
  for (int p = 0; p < 2; ++p) {
    const int c = tid + p * 256;
    const int r = c & 127, qd = c >> 7;
    li_[p] = (r >> 4) * 64 + qd * 16 + (r & 15);
    ga_[p] = (size_t)(m0 + r) * DMOD + qd * 8;
    gw_[p] = (size_t)(n0 + r) * DMOD + qd * 8;
  }
  half8 pah[2], pal[2], pwh[2], pwl[2];
  #pragma unroll
  for (int p = 0; p < 2; ++p) {
    pah[p] = *(const half8*)(Ah + ga_[p]);
    pal[p] = *(const half8*)(Al + ga_[p]);
    pwh[p] = *(const half8*)(wh + gw_[p]);
    pwl[p] = *(const half8*)(wl + gw_[p]);
  }
  for (int k0 = 0; k0 < DMOD; k0 += 32) {
    #pragma unroll
    for (int p = 0; p < 2; ++p) {
      As_h[li_[p]] = pah[p];
      As_l[li_[p]] = pal[p];
      Ws_h[li_[p]] = pwh[p];
      Ws_l[li_[p]] = pwl[p];
    }
    __syncthreads();
    if (k0 + 32 < DMOD) {   // prefetch next slab; latency hidden under MFMA
      #pragma unroll
      for (int p = 0; p < 2; ++p) {
        pah[p] = *(const half8*)(Ah + ga_[p] + k0 + 32);
        pal[p] = *(const half8*)(Al + ga_[p] + k0 + 32);
        pwh[p] = *(const half8*)(wh + gw_[p] + k0 + 32);
        pwl[p] = *(const half8*)(wl + gw_[p] + k0 + 32);
      }
    }
    half8 afh[4], afl[4], wfh[4], wfl[4];
    #pragma unroll
    for (int i = 0; i < 4; ++i) {
      afh[i] = As_h[(wm + i) * 64 + lane];
      afl[i] = As_l[(wm + i) * 64 + lane];
      wfh[i] = Ws_h[(wn + i) * 64 + lane];
      wfl[i] = Ws_l[(wn + i) * 64 + lane];
    }
    #pragma unroll
    for (int i = 0; i < 4; ++i)
      #pragma unroll
      for (int j = 0; j < 4; ++j) {
        acc[i][j] = MFMA16(afh[i], wfh[j], acc[i][j]);
        acc[i][j] = MFMA16(afh[i], wfl[j], acc[i][j]);
        acc[i][j] = MFMA16(afl[i], wfh[j], acc[i][j]);
      }
    __syncthreads();
  }
  // vectorized epilogue: 4 passes, LDS restage [32][136], coalesced half8 stores
  const int cr = (lane >> 4) * 4;
  const int cc = lane & 15;
  _Float16* Eh = smem;
  _Float16* El = smem + 4352;
  #pragma unroll
  for (int ip = 0; ip < 4; ++ip) {
    #pragma unroll
    for (int j = 0; j < 4; ++j) {
      const int col = (wn + j) * 16 + cc;
      #pragma unroll
      for (int r = 0; r < 4; ++r) {
        const float val = acc[ip][j][r];
        const _Float16 h = (_Float16)val;
        const int lr = (w >> 1) * 16 + cr + r;
        Eh[lr * 136 + col] = h;
        El[lr * 136 + col] = (_Float16)(val - (float)h);
      }
    }
    __syncthreads();
    #pragma unroll
    for (int e = 0; e < 2; ++e) {
      const int idx = tid + e * 256;       // 0..511
      const int lr = idx >> 4;             // 0..31
      const int cg = idx & 15;
      const int gr = m0 + (lr >> 4) * 64 + ip * 16 + (lr & 15);
      const size_t go = (size_t)gr * DMOD + n0 + cg * 8;
      *(half8*)(hB + go) = *(const half8*)&Eh[lr * 136 + cg * 8];
      *(half8*)(lB + go) = *(const half8*)&El[lr * 136 + cg * 8];
    }
    __syncthreads();
  }
}

// ---------------- per-bh transpose: v[bh][s][d] -> vt[bh][d][s] -----------------
// (bh blocks are the faithful flat view: 32768 contiguous elements each)
__global__ __launch_bounds__(256) void k_vt(
    const _Float16* __restrict__ vh, const _Float16* __restrict__ vl,
    _Float16* __restrict__ vth, _Float16* __restrict__ vtl) {
  const int bh = blockIdx.x;
  const size_t off = (size_t)bh * 32768;
  __shared__ _Float16 Th[64][66], Tl[64][66];
  const int tid = threadIdx.x;
  const int c0 = blockIdx.y * 4;
  for (int c = c0; c < c0 + 4; ++c) {
    const int sc = c * 64;
    #pragma unroll
    for (int p = 0; p < 2; ++p) {
      const int lin = tid + p * 256;
      const int r = lin >> 3, g = lin & 7;
      *(half8*)&Th[r][g * 8] = *(const half8*)(vh + off + (size_t)(sc + r) * 64 + g * 8);
      *(half8*)&Tl[r][g * 8] = *(const half8*)(vl + off + (size_t)(sc + r) * 64 + g * 8);
    }
    __syncthreads();
    #pragma unroll
    for (int p = 0; p < 2; ++p) {
      const int lin = tid + p * 256;
      const int d = lin >> 3, sg = lin & 7;
      half8 hv, lv;
      #pragma unroll
      for (int j = 0; j < 8; ++j) {
        hv[j] = Th[sg * 8 + j][d];
        lv[j] = Tl[sg * 8 + j][d];
      }
      *(half8*)(vth + off + (size_t)d * 512 + sc + sg * 8) = hv;
      *(half8*)(vtl + off + (size_t)d * 512 + sc + sg * 8) = lv;
    }
    __syncthreads();
  }
}

// ---------------- FC GEMM (fp32 out + hi/lo residual), split-fp16 MFMA ----------
__global__ __launch_bounds__(256) void k_gemm_fc(
    const _Float16* __restrict__ Ah, const _Float16* __restrict__ Al,
    const _Float16* __restrict__ wh, const _Float16* __restrict__ wl,
    float* __restrict__ C,
    const _Float16* __restrict__ resh, const _Float16* __restrict__ resl) {
  const int m0 = blockIdx.x * 128;
  const int n0 = blockIdx.y * 128;
  const int tid = threadIdx.x;
  const int lane = tid & 63;
  const int w = tid >> 6;
  const int wm = (w >> 1) * 4;
  const int wn = (w & 1) * 4;
  __shared__ half8 As_h[512], As_l[512], Ws_h[512], Ws_l[512];
  float4v acc[4][4];
  #pragma unroll
  for (int i = 0; i < 4; ++i)
    #pragma unroll
    for (int j = 0; j < 4; ++j)
      acc[i][j] = (float4v){0.f, 0.f, 0.f, 0.f};
  int li_[2]; size_t ga_[2], gw_[2];
  #pragma unroll
  for (int p = 0; p < 2; ++p) {
    const int c = tid + p * 256;
    const int r = c & 127, qd = c >> 7;
    li_[p] = (r >> 4) * 64 + qd * 16 + (r & 15);
    ga_[p] = (size_t)(m0 + r) * DMOD + qd * 8;
    gw_[p] = (size_t)(n0 + r) * DMOD + qd * 8;
  }
  half8 pah[2], pal[2], pwh[2], pwl[2];
  #pragma unroll
  for (int p = 0; p < 2; ++p) {
    pah[p] = *(const half8*)(Ah + ga_[p]);
    pal[p] = *(const half8*)(Al + ga_[p]);
    pwh[p] = *(const half8*)(wh + gw_[p]);
    pwl[p] = *(const half8*)(wl + gw_[p]);
  }
  for (int k0 = 0; k0 < DMOD; k0 += 32) {
    #pragma unroll
    for (int p = 0; p < 2; ++p) {
      As_h[li_[p]] = pah[p];
      As_l[li_[p]] = pal[p];
      Ws_h[li_[p]] = pwh[p];
      Ws_l[li_[p]] = pwl[p];
    }
    __syncthreads();
    if (k0 + 32 < DMOD) {
      #pragma unroll
      for (int p = 0; p < 2; ++p) {
        pah[p] = *(const half8*)(Ah + ga_[p] + k0 + 32);
        pal[p] = *(const half8*)(Al + ga_[p] + k0 + 32);
        pwh[p] = *(const half8*)(wh + gw_[p] + k0 + 32);
        pwl[p] = *(const half8*)(wl + gw_[p] + k0 + 32);
      }
    }
    half8 afh[4], afl[4], wfh[4], wfl[4];
    #pragma unroll
    for (int i = 0; i < 4; ++i) {
      afh[i] = As_h[(wm + i) * 64 + lane];
      afl[i] = As_l[(wm + i) * 64 + lane];
      wfh[i] = Ws_h[(wn + i) * 64 + lane];
      wfl[i] = Ws_l[(wn + i) * 64 + lane];
    }
    #pragma unroll
    for (int i = 0; i < 4; ++i)
      #pragma unroll
      for (int j = 0; j < 4; ++j) {
        acc[i][j] = MFMA16(afh[i], wfh[j], acc[i][j]);
        acc[i][j] = MFMA16(afh[i], wfl[j], acc[i][j]);
        acc[i][j] = MFMA16(afl[i], wfh[j], acc[i][j]);
      }
    __syncthreads();
  }
  const int cr = (lane >> 4) * 4;
  const int cc = lane & 15;
  #pragma unroll
  for (int i = 0; i < 4; ++i) {
    const int gm = m0 + (wm + i) * 16 + cr;
    #pragma unroll
    for (int j = 0; j < 4; ++j) {
      const int gc = n0 + (wn + j) * 16 + cc;
      #pragma unroll
      for (int r = 0; r < 4; ++r) {
        const size_t flat = (size_t)(gm + r) * DMOD + gc;
        C[flat] = acc[i][j][r] + (float)resh[flat] + (float)resl[flat];
      }
    }
  }
}

// ---------------- MFMA attention per (bh, q-tile of 64) -------------------------
// Padded frag-order LDS (group stride 17) -> conflict-free staging.
// Q frags hoisted to registers; Q LDS arrays reused for P. 3 blocks/CU.
__global__ __launch_bounds__(256, 3) void k_attn(
    const _Float16* __restrict__ qh, const _Float16* __restrict__ ql,
    const _Float16* __restrict__ kh, const _Float16* __restrict__ kl,
    const _Float16* __restrict__ vth, const _Float16* __restrict__ vtl,
    const unsigned int* __restrict__ pk,
    _Float16* __restrict__ oh, _Float16* __restrict__ ol) {
  const int bh = blockIdx.x;
  const int q0 = blockIdx.y * 64;
  const size_t bhoff = (size_t)bh * 32768;
  __shared__ half8 QPh[544], QPl[544];          // Q staging, then P
  __shared__ half8 Kh_s[544], Kl_s[544], Vh_s[544], Vl_s[544];
  __shared__ unsigned int Ms[64][2];
  __shared__ float Ps[4][64];
  __shared__ float lsum[64];
  const int tid = threadIdx.x;
  const int w = tid >> 6;
  const int lane = tid & 63;
  const int l15 = lane & 15;
  const int quad = lane >> 4;
  #pragma unroll
  for (int p = 0; p < 2; ++p) {
    const int lin = tid + p * 256;
    const int r = lin >> 3, g = lin & 7;
    const int fi = (r >> 4) * 128 + g * 16 + (r & 15);
    const size_t ga = bhoff + (size_t)(q0 + r) * 64 + g * 8;
    QPh[PG(fi)] = *(const half8*)(qh + ga);
    QPl[PG(fi)] = *(const half8*)(ql + ga);
  }
  __syncthreads();
  half8 qfh[4][2], qfl[4][2];
  #pragma unroll
  for (int ns = 0; ns < 4; ++ns) {
    const int gq = ns * 8 + quad;
    qfh[ns][0] = QPh[gq * 17 + l15];
    qfh[ns][1] = QPh[(gq + 4) * 17 + l15];
    qfl[ns][0] = QPl[gq * 17 + l15];
    qfl[ns][1] = QPl[(gq + 4) * 17 + l15];
  }
  float4v oacc[4];
  float lsw[4] = {0.f, 0.f, 0.f, 0.f};
  #pragma unroll
  for (int ns = 0; ns < 4; ++ns) oacc[ns] = (float4v){0.f, 0.f, 0.f, 0.f};
  for (int kc = 0; kc < SLEN; kc += 64) {
    __syncthreads();
    #pragma unroll
    for (int p = 0; p < 2; ++p) {
      const int lin = tid + p * 256;
      const int r = lin >> 3, g = lin & 7;
      const int fi = PG((r >> 4) * 128 + g * 16 + (r & 15));
      const size_t gk = bhoff + (size_t)(kc + r) * 64 + g * 8;
      const size_t gv = bhoff + (size_t)r * 512 + kc + g * 8;
      Kh_s[fi] = *(const half8*)(kh + gk);
      Kl_s[fi] = *(const half8*)(kl + gk);
      Vh_s[fi] = *(const half8*)(vth + gv);
      Vl_s[fi] = *(const half8*)(vtl + gv);
    }
    if (tid < 128)
      Ms[tid >> 1][tid & 1] =
          pk[((size_t)((bh >> 2) << 9) + q0 + (tid >> 1)) * 16 + (kc >> 5) + (tid & 1)];
    __syncthreads();
    const int ga0 = (w * 8 + quad) * 17 + l15;
    const int ga1 = (w * 8 + quad + 4) * 17 + l15;
    const half8 ah0 = Kh_s[ga0], ah1 = Kh_s[ga1];
    const half8 al0 = Kl_s[ga0], al1 = Kl_s[ga1];
    #pragma unroll
    for (int ns = 0; ns < 4; ++ns) {
      float4v s = (float4v){0.f, 0.f, 0.f, 0.f};
      s = MFMA16(ah0, qfh[ns][0], s); s = MFMA16(ah1, qfh[ns][1], s);
      s = MFMA16(ah0, qfl[ns][0], s); s = MFMA16(ah1, qfl[ns][1], s);
      s = MFMA16(al0, qfh[ns][0], s); s = MFMA16(al1, qfh[ns][1], s);
      const int q = ns * 16 + l15;
      const unsigned long long mrow = *(const unsigned long long*)&Ms[q][0];
      const unsigned mbits = (unsigned)(mrow >> (w * 16 + quad * 4)) & 15u;
      float pv[4];
      #pragma unroll
      for (int r = 0; r < 4; ++r) {
        const float pe = ((mbits >> r) & 1u) ? __expf(s[r] * 0.125f) : 0.f;
        pv[r] = pe;
        lsw[ns] += pe;
      }
      half4 h4, l4;
      #pragma unroll
      for (int r = 0; r < 4; ++r) {
        h4[r] = (_Float16)pv[r];
        l4[r] = (_Float16)(pv[r] - (float)h4[r]);
      }
      const int hb = ((ns * 8 + w * 2 + (quad >> 1)) * 17 + l15) * 8 + (quad & 1) * 4;
      *(half4*)((_Float16*)QPh + hb) = h4;
      *(half4*)((_Float16*)QPl + hb) = l4;
    }
    __syncthreads();
    const half8 vh0 = Vh_s[ga0], vh1 = Vh_s[ga1];
    const half8 vl0 = Vl_s[ga0], vl1 = Vl_s[ga1];
    #pragma unroll
    for (int ns = 0; ns < 4; ++ns) {
      const int pb0 = (ns * 8 + quad) * 17 + l15;
      const int pb1 = (ns * 8 + quad + 4) * 17 + l15;
      const half8 ph0 = QPh[pb0], ph1 = QPh[pb1];
      const half8 pl0 = QPl[pb0], pl1 = QPl[pb1];
      oacc[ns] = MFMA16(vh0, ph0, oacc[ns]); oacc[ns] = MFMA16(vh1, ph1, oacc[ns]);
      oacc[ns] = MFMA16(vh0, pl0, oacc[ns]); oacc[ns] = MFMA16(vh1, pl1, oacc[ns]);
      oacc[ns] = MFMA16(vl0, ph0, oacc[ns]); oacc[ns] = MFMA16(vl1, ph1, oacc[ns]);
    }
  }
  #pragma unroll
  for (int ns = 0; ns < 4; ++ns) {
    lsw[ns] += __shfl_xor(lsw[ns], 16);
    lsw[ns] += __shfl_xor(lsw[ns], 32);
  }
  __syncthreads();
  if (quad == 0) {
    #pragma unroll
    for (int ns = 0; ns < 4; ++ns) Ps[w][ns * 16 + l15] = lsw[ns];
  }
  __syncthreads();
  if (tid < 64) lsum[tid] = Ps[0][tid] + Ps[1][tid] + Ps[2][tid] + Ps[3][tid];
  __syncthreads();
  const int b = bh >> 2, h = bh & 3;
  #pragma unroll
  for (int ns = 0; ns < 4; ++ns) {
    const int q = ns * 16 + l15;
    const float inv = 1.0f / lsum[q];
    const size_t base =
        ((size_t)(b * SLEN + q0 + q)) * DMOD + h * HDIM + w * 16 + quad * 4;
    half4 h4, l4;
    #pragma unroll
    for (int r = 0; r < 4; ++r) {
      const float v = oacc[ns][r] * inv;
      h4[r] = (_Float16)v;
      l4[r] = (_Float16)(v - (float)h4[r]);
    }
    *(half4*)(oh + base) = h4;
    *(half4*)(ol + base) = l4;
  }
}

// ---------------- layer norm + zero invalid rows ----------------
__global__ __launch_bounds__(256) void k_ln(
    const float* __restrict__ Y, const int* __restrict__ lengths,
    const float* __restrict__ g, const float* __restrict__ bb,
    float* __restrict__ out) {
  const int row = blockIdx.x * 4 + (threadIdx.x >> 6);
  const int lane = threadIdx.x & 63;
  const int b = row >> 9, s = row & 511;
  const float* yr = Y + (size_t)row * DMOD;
  float v[4];
  *(float4*)v = *(const float4*)(yr + lane * 4);
  float sum = v[0] + v[1] + v[2] + v[3];
  #pragma unroll
  for (int off = 32; off > 0; off >>= 1) sum += __shfl_xor(sum, off);
  const float mu = sum * (1.0f / DMOD);
  float vs = 0.f;
  #pragma unroll
  for (int i = 0; i < 4; ++i) { const float dx = v[i] - mu; vs += dx * dx; }
  #pragma unroll
  for (int off = 32; off > 0; off >>= 1) vs += __shfl_xor(vs, off);
  const float inv = rsqrtf(vs * (1.0f / DMOD) + 1e-5f);
  const bool valid = s < lengths[b];
  float gg[4], bv[4], ov[4];
  *(float4*)gg = *(const float4*)(g + lane * 4);
  *(float4*)bv = *(const float4*)(bb + lane * 4);
  #pragma unroll
  for (int i = 0; i < 4; ++i)
    ov[i] = valid ? ((v[i] - mu) * inv * gg[i] + bv[i]) : 0.f;
  *(float4*)(out + (size_t)row * DMOD + lane * 4) = *(float4*)ov;
}

// ---------------- triangular temporal pooling, 4 bins fused, s-chunked ----------
__global__ __launch_bounds__(256) void k_pool(
    const float* __restrict__ X, const int* __restrict__ lengths,
    float* __restrict__ Up) {
  const int b = blockIdx.x;
  const int c = blockIdx.y;
  const int d = threadIdx.x;
  const float inv4 = 4.0f / (float)lengths[b];
  float a0 = 0.f, a1 = 0.f, a2 = 0.f, a3 = 0.f;
  for (int s = c * 128; s < c * 128 + 128; ++s) {
    const float sv = (float)(s + 1) * inv4;
    const float xv = X[((size_t)b * SLEN + s) * DMOD + d];
    float t;
    t = 1.0f - fabsf(sv - 1.0f) * 0.25f; a0 += t * t * xv;
    t = 1.0f - fabsf(sv - 2.0f) * 0.25f; a1 += t * t * xv;
    t = 1.0f - fabsf(sv - 3.0f) * 0.25f; a2 += t * t * xv;
    t = 1.0f - fabsf(sv - 4.0f) * 0.25f; a3 += t * t * xv;
  }
  float* up = Up + (((size_t)b * 4 + c) * 4) * DMOD + d;
  up[0 * DMOD] = a0; up[1 * DMOD] = a1; up[2 * DMOD] = a2; up[3 * DMOD] = a3;
}

// ---------------- final [32,1024] @ [1024,2]^T + bias ---------------------------
__global__ __launch_bounds__(256) void k_out(
    const float* __restrict__ Up, const float* __restrict__ ow,
    const float* __restrict__ ob, float* __restrict__ out) {
  const int tid = threadIdx.x;
  const int pair = tid >> 2;
  const int part = tid & 3;
  const int b = pair >> 1, i = pair & 1;
  const float* upb = Up + ((size_t)b * 16 + part) * DMOD;
  const float* wb = ow + (size_t)i * 1024 + part * DMOD;
  float acc = 0.f;
  for (int d = 0; d < DMOD; d += 4) {
    const float4 u0 = *(const float4*)(upb + d);
    const float4 u1 = *(const float4*)(upb + 4 * DMOD + d);
    const float4 u2 = *(const float4*)(upb + 8 * DMOD + d);
    const float4 u3 = *(const float4*)(upb + 12 * DMOD + d);
    const float4 w = *(const float4*)(wb + d);
    acc += (u0.x + u1.x + u2.x + u3.x) * w.x + (u0.y + u1.y + u2.y + u3.y) * w.y +
           (u0.z + u1.z + u2.z + u3.z) * w.z + (u0.w + u1.w + u2.w + u3.w) * w.w;
  }
  acc += __shfl_xor(acc, 1);
  acc += __shfl_xor(acc, 2);
  if (part == 0) out[b * 2 + i] = acc + ob[i];
}

extern "C" void kernel_launch(void* const* d_in, const int* in_sizes, int n_in,
                              void* d_out, int out_size, void* d_ws, size_t ws_size,
                              hipStream_t stream) {
  const int* seqs     = (const int*)d_in[0];
  const int* masks    = (const int*)d_in[1];
  const int* lengths  = (const int*)d_in[2];
  const float* emb    = (const float*)d_in[5];
  const float* bias   = (const float*)d_in[6];
  const float* pe     = (const float*)d_in[7];
  const float* Wq     = (const float*)d_in[8];
  const float* Wk     = (const float*)d_in[9];
  const float* Wv     = (const float*)d_in[10];
  const float* Wfc    = (const float*)d_in[11];
  const float* ln_g   = (const float*)d_in[12];
  const float* ln_b   = (const float*)d_in[13];
  const float* out_w  = (const float*)d_in[14];
  const float* out_b  = (const float*)d_in[15];
  float* outp = (float*)d_out;

  const size_t NE = (size_t)BSZ * SLEN * DMOD;   // 4,194,304
  _Float16* qh = (_Float16*)d_ws;
  _Float16* ql = qh + NE;
  _Float16* kh = ql + NE;
  _Float16* kl = kh + NE;
  _Float16* vh = kl + NE;
  _Float16* vl = vh + NE;
  _Float16* vth = vl + NE;
  _Float16* vtl = vth + NE;
  _Float16* xh = vtl + NE;
  _Float16* xl = xh + NE;
  _Float16* oh = xl + NE;
  _Float16* ol = oh + NE;
  _Float16* wh = ol + NE;                        // 4*65536 halfs
  _Float16* wl = wh + 4 * 65536;
  unsigned int* pk = (unsigned int*)(wl + 4 * 65536);
  float* Up = (float*)(pk + BSZ * SLEN * 16);
  float* y = (float*)qh;                         // alias: qh/ql dead after attn

  k_embed<<<BSZ * SLEN / 4, 256, 0, stream>>>(seqs, lengths, emb, bias, pe, xh, xl);
  k_wsplit<<<dim3(32, 4), 256, 0, stream>>>(Wq, Wk, Wv, Wfc, wh, wl);
  k_maskpack<<<BSZ * SLEN, 256, 0, stream>>>(masks, pk);
  k_gemm_qkv<<<dim3(128, 2, 3), 256, 0, stream>>>(
      xh, xl, wh, wl, qh, ql, kh, kl, vh, vl);
  k_vt<<<dim3(BSZ * NH, 2), 256, 0, stream>>>(vh, vl, vth, vtl);
  k_attn<<<dim3(BSZ * NH, SLEN / 64), 256, 0, stream>>>(
      qh, ql, kh, kl, vth, vtl, pk, oh, ol);
  k_gemm_fc<<<dim3(128, 2), 256, 0, stream>>>(
      oh, ol, wh + 3 * 65536, wl + 3 * 65536, y, xh, xl);
  k_ln<<<BSZ * SLEN / 4, 256, 0, stream>>>(y, lengths, ln_g, ln_b, y);
  k_pool<<<dim3(BSZ, 4), 256, 0, stream>>>(y, lengths, Up);
  k_out<<<1, 256, 0, stream>>>(Up, out_w, out_b, outp);
}

// Round 11
// 301.253 us; speedup vs baseline: 4.5892x; 1.0701x over previous
//
#include <hip/hip_runtime.h>

#define BSZ 32
#define SLEN 512
#define CLEN 20
#define DMOD 256
#define NH 4
#define HDIM 64

typedef _Float16 half8 __attribute__((ext_vector_type(8)));
typedef _Float16 half4 __attribute__((ext_vector_type(4)));
typedef float float4v __attribute__((ext_vector_type(4)));

#define MFMA16(a, b, c) __builtin_amdgcn_mfma_f32_16x16x32_f16(a, b, c, 0, 0, 0)
// padded half8 index: groups of 16 half8 get stride 17 (breaks 256B-stride conflicts)
#define PG(fi) ((((fi) >> 4) * 17) + ((fi) & 15))

// ---------------- embedding sum + positional encoding -> fp16 ------------------
__global__ __launch_bounds__(256) void k_embed(
    const int* __restrict__ seqs, const int* __restrict__ lengths,
    const float* __restrict__ emb, const float* __restrict__ bias,
    const float* __restrict__ pe, _Float16* __restrict__ x) {
  const int row0 = blockIdx.x * 4;
  const int sub = threadIdx.x >> 6;
  const int lane = threadIdx.x & 63;
  const int row = row0 + sub;
  const int b = row >> 9, s = row & 511;
  __shared__ int codes[4][CLEN];
  if (threadIdx.x < 4 * CLEN)
    codes[threadIdx.x / CLEN][threadIdx.x % CLEN] = seqs[row0 * CLEN + threadIdx.x];
  __syncthreads();
  const int pos = (s < lengths[b]) ? (s + 1) : 0;
  const int d = lane * 4;
  float4 acc = *(const float4*)(bias + d);
  const float4 pv = *(const float4*)(pe + (size_t)pos * DMOD + d);
  acc.x += pv.x; acc.y += pv.y; acc.z += pv.z; acc.w += pv.w;
  #pragma unroll
  for (int c = 0; c < CLEN; ++c) {
    const float4 ev = *(const float4*)(emb + (size_t)codes[sub][c] * DMOD + d);
    acc.x += ev.x; acc.y += ev.y; acc.z += ev.z; acc.w += ev.w;
  }
  half4 hv;
  hv[0] = (_Float16)acc.x; hv[1] = (_Float16)acc.y;
  hv[2] = (_Float16)acc.z; hv[3] = (_Float16)acc.w;
  *(half4*)(x + (size_t)row * DMOD + d) = hv;
}

// ---------------- cast 4 weight matrices [256x256] fp32 -> fp16 ----------------
__global__ __launch_bounds__(256) void k_wsplit(
    const float* __restrict__ W0, const float* __restrict__ W1,
    const float* __restrict__ W2, const float* __restrict__ W3,
    _Float16* __restrict__ wh) {
  const int z = blockIdx.y;
  const float* W = (z == 0) ? W0 : (z == 1) ? W1 : (z == 2) ? W2 : W3;
  const int idx = (blockIdx.x * 256 + threadIdx.x) * 8;
  float v[8];
  *(float4*)v = *(const float4*)(W + idx);
  *(float4*)(v + 4) = *(const float4*)(W + idx + 4);
  half8 h;
  #pragma unroll
  for (int i = 0; i < 8; ++i) h[i] = (_Float16)v[i];
  *(half8*)(wh + (size_t)z * 65536 + idx) = h;
}

// ---------------- bit-pack attention mask: [32,512,512] int -> [32,512,16] u32 ----
__global__ __launch_bounds__(256) void k_maskpack(
    const int* __restrict__ masks, unsigned int* __restrict__ pk) {
  const int bq = blockIdx.x;
  const int wv = threadIdx.x >> 6;
  const int lane = threadIdx.x & 63;
  #pragma unroll
  for (int p = 0; p < 2; ++p) {
    const int chunk = wv + p * 4;
    const int m = masks[(size_t)bq * SLEN + chunk * 64 + lane];
    const unsigned long long bal = __ballot(m != 0);
    if (lane == 0) {
      pk[(size_t)bq * 16 + chunk * 2]     = (unsigned int)bal;
      pk[(size_t)bq * 16 + chunk * 2 + 1] = (unsigned int)(bal >> 32);
    }
  }
}

// ---------------- QKV GEMM: fp16 MFMA, prefetch, vectorized epilogue ------------
__global__ __launch_bounds__(256) void k_gemm_qkv(
    const _Float16* __restrict__ A, const _Float16* __restrict__ Wb,
    _Float16* __restrict__ q, _Float16* __restrict__ k, _Float16* __restrict__ v) {
  const int z = blockIdx.z;
  _Float16* Cb = (z == 0) ? q : (z == 1) ? k : v;
  const _Float16* w_ = Wb + (size_t)z * 65536;
  const int m0 = blockIdx.x * 128;
  const int n0 = blockIdx.y * 128;
  const int tid = threadIdx.x;
  const int lane = tid & 63;
  const int w = tid >> 6;
  const int wm = (w >> 1) * 4;
  const int wn = (w & 1) * 4;
  __shared__ _Float16 smem[8704];               // 17 KB: staging; epilogue reuse
  half8* As = (half8*)(smem);
  half8* Ws = (half8*)(smem + 4096);
  float4v acc[4][4];
  #pragma unroll
  for (int i = 0; i < 4; ++i)
    #pragma unroll
    for (int j = 0; j < 4; ++j)
      acc[i][j] = (float4v){0.f, 0.f, 0.f, 0.f};
  int li_[2]; size_t ga_[2], gw_[2];
  #pragma unroll
  for (int p = 0; p < 2; ++p) {
    const int c = tid + p * 256;
    const int r = c & 127, qd = c >> 7;
    li_[p] = (r >> 4) * 64 + qd * 16 + (r & 15);
    ga_[p] = (size_t)(m0 + r) * DMOD + qd * 8;
    gw_[p] = (size_t)(n0 + r) * DMOD + qd * 8;
  }
  half8 pa[2], pw[2];
  #pragma unroll
  for (int p = 0; p < 2; ++p) {
    pa[p] = *(const half8*)(A + ga_[p]);
    pw[p] = *(const half8*)(w_ + gw_[p]);
  }
  for (int k0 = 0; k0 < DMOD; k0 += 32) {
    #pragma unroll
    for (int p = 0; p < 2; ++p) {
      As[li_[p]] = pa[p];
      Ws[li_[p]] = pw[p];
    }
    __syncthreads();
    if (k0 + 32 < DMOD) {   // prefetch next slab; latency hidden under MFMA
      #pragma unroll
      for (int p = 0; p < 2; ++p) {
        pa[p] = *(const half8*)(A + ga_[p] + k0 + 32);
        pw[p] = *(const half8*)(w_ + gw_[p] + k0 + 32);
      }
    }
    half8 af[4], wf[4];
    #pragma unroll
    for (int i = 0; i < 4; ++i) {
      af[i] = As[(wm + i) * 64 + lane];
      wf[i] = Ws[(wn + i) * 64 + lane];
    }
    #pragma unroll
    for (int i = 0; i < 4; ++i)
      #pragma unroll
      for (int j = 0; j < 4; ++j)
        acc[i][j] = MFMA16(af[i], wf[j], acc[i][j]);
    __syncthreads();
  }
  // vectorized epilogue: 4 passes, LDS restage [32][136], coalesced half8 stores
  const int cr = (lane >> 4) * 4;
  const int cc = lane & 15;
  _Float16* Eh = smem;
  #pragma unroll
  for (int ip = 0; ip < 4; ++ip) {
    #pragma unroll
    for (int j = 0; j < 4; ++j) {
      const int col = (wn + j) * 16 + cc;
      #pragma unroll
      for (int r = 0; r < 4; ++r)
        Eh[((w >> 1) * 16 + cr + r) * 136 + col] = (_Float16)acc[ip][j][r];
    }
    __syncthreads();
    #pragma unroll
    for (int e = 0; e < 2; ++e) {
      const int idx = tid + e * 256;       // 0..511
      const int lr = idx >> 4;             // 0..31
      const int cg = idx & 15;
      const int gr = m0 + (lr >> 4) * 64 + ip * 16 + (lr & 15);
      *(half8*)(Cb + (size_t)gr * DMOD + n0 + cg * 8) =
          *(const half8*)&Eh[lr * 136 + cg * 8];
    }
    __syncthreads();
  }
}

// ---------------- per-bh transpose: v[bh][s][d] -> vt[bh][d][s] -----------------
__global__ __launch_bounds__(256) void k_vt(
    const _Float16* __restrict__ v, _Float16* __restrict__ vt) {
  const int bh = blockIdx.x;
  const size_t off = (size_t)bh * 32768;
  __shared__ _Float16 Th[64][66];
  const int tid = threadIdx.x;
  const int c0 = blockIdx.y * 4;
  for (int c = c0; c < c0 + 4; ++c) {
    const int sc = c * 64;
    #pragma unroll
    for (int p = 0; p < 2; ++p) {
      const int lin = tid + p * 256;
      const int r = lin >> 3, g = lin & 7;
      *(half8*)&Th[r][g * 8] = *(const half8*)(v + off + (size_t)(sc + r) * 64 + g * 8);
    }
    __syncthreads();
    #pragma unroll
    for (int p = 0; p < 2; ++p) {
      const int lin = tid + p * 256;
      const int d = lin >> 3, sg = lin & 7;
      half8 hv;
      #pragma unroll
      for (int j = 0; j < 8; ++j) hv[j] = Th[sg * 8 + j][d];
      *(half8*)(vt + off + (size_t)d * 512 + sc + sg * 8) = hv;
    }
    __syncthreads();
  }
}

// ---------------- FC GEMM (fp32 out + fp16 residual), fp16 MFMA -----------------
__global__ __launch_bounds__(256) void k_gemm_fc(
    const _Float16* __restrict__ A, const _Float16* __restrict__ w_,
    float* __restrict__ C, const _Float16* __restrict__ res) {
  const int m0 = blockIdx.x * 128;
  const int n0 = blockIdx.y * 128;
  const int tid = threadIdx.x;
  const int lane = tid & 63;
  const int w = tid >> 6;
  const int wm = (w >> 1) * 4;
  const int wn = (w & 1) * 4;
  __shared__ half8 As[512], Ws[512];
  float4v acc[4][4];
  #pragma unroll
  for (int i = 0; i < 4; ++i)
    #pragma unroll
    for (int j = 0; j < 4; ++j)
      acc[i][j] = (float4v){0.f, 0.f, 0.f, 0.f};
  int li_[2]; size_t ga_[2], gw_[2];
  #pragma unroll
  for (int p = 0; p < 2; ++p) {
    const int c = tid + p * 256;
    const int r = c & 127, qd = c >> 7;
    li_[p] = (r >> 4) * 64 + qd * 16 + (r & 15);
    ga_[p] = (size_t)(m0 + r) * DMOD + qd * 8;
    gw_[p] = (size_t)(n0 + r) * DMOD + qd * 8;
  }
  half8 pa[2], pw[2];
  #pragma unroll
  for (int p = 0; p < 2; ++p) {
    pa[p] = *(const half8*)(A + ga_[p]);
    pw[p] = *(const half8*)(w_ + gw_[p]);
  }
  for (int k0 = 0; k0 < DMOD; k0 += 32) {
    #pragma unroll
    for (int p = 0; p < 2; ++p) {
      As[li_[p]] = pa[p];
      Ws[li_[p]] = pw[p];
    }
    __syncthreads();
    if (k0 + 32 < DMOD) {
      #pragma unroll
      for (int p = 0; p < 2; ++p) {
        pa[p] = *(const half8*)(A + ga_[p] + k0 + 32);
        pw[p] = *(const half8*)(w_ + gw_[p] + k0 + 32);
      }
    }
    half8 af[4], wf[4];
    #pragma unroll
    for (int i = 0; i < 4; ++i) {
      af[i] = As[(wm + i) * 64 + lane];
      wf[i] = Ws[(wn + i) * 64 + lane];
    }
    #pragma unroll
    for (int i = 0; i < 4; ++i)
      #pragma unroll
      for (int j = 0; j < 4; ++j)
        acc[i][j] = MFMA16(af[i], wf[j], acc[i][j]);
    __syncthreads();
  }
  const int cr = (lane >> 4) * 4;
  const int cc = lane & 15;
  #pragma unroll
  for (int i = 0; i < 4; ++i) {
    const int gm = m0 + (wm + i) * 16 + cr;
    #pragma unroll
    for (int j = 0; j < 4; ++j) {
      const int gc = n0 + (wn + j) * 16 + cc;
      #pragma unroll
      for (int r = 0; r < 4; ++r) {
        const size_t flat = (size_t)(gm + r) * DMOD + gc;
        C[flat] = acc[i][j][r] + (float)res[flat];
      }
    }
  }
}

// ---------------- MFMA attention per (bh, q-tile of 64), fp16 -------------------
// Padded frag-order LDS (group stride 17), Q frags in registers, Q LDS reused
// for P. ~28 KB LDS -> 5 blocks/CU.
__global__ __launch_bounds__(256, 4) void k_attn(
    const _Float16* __restrict__ q_, const _Float16* __restrict__ k_,
    const _Float16* __restrict__ vt, const unsigned int* __restrict__ pk,
    _Float16* __restrict__ o) {
  const int bh = blockIdx.x;
  const int q0 = blockIdx.y * 64;
  const size_t bhoff = (size_t)bh * 32768;
  __shared__ half8 QP[544];                     // Q staging, then P
  __shared__ half8 Ks[544], Vs[544];
  __shared__ unsigned int Ms[64][2];
  __shared__ float Ps[4][64];
  __shared__ float lsum[64];
  const int tid = threadIdx.x;
  const int w = tid >> 6;
  const int lane = tid & 63;
  const int l15 = lane & 15;
  const int quad = lane >> 4;
  #pragma unroll
  for (int p = 0; p < 2; ++p) {
    const int lin = tid + p * 256;
    const int r = lin >> 3, g = lin & 7;
    const int fi = (r >> 4) * 128 + g * 16 + (r & 15);
    QP[PG(fi)] = *(const half8*)(q_ + bhoff + (size_t)(q0 + r) * 64 + g * 8);
  }
  __syncthreads();
  half8 qf[4][2];
  #pragma unroll
  for (int ns = 0; ns < 4; ++ns) {
    const int gq = ns * 8 + quad;
    qf[ns][0] = QP[gq * 17 + l15];
    qf[ns][1] = QP[(gq + 4) * 17 + l15];
  }
  float4v oacc[4];
  float lsw[4] = {0.f, 0.f, 0.f, 0.f};
  #pragma unroll
  for (int ns = 0; ns < 4; ++ns) oacc[ns] = (float4v){0.f, 0.f, 0.f, 0.f};
  for (int kc = 0; kc < SLEN; kc += 64) {
    __syncthreads();
    #pragma unroll
    for (int p = 0; p < 2; ++p) {
      const int lin = tid + p * 256;
      const int r = lin >> 3, g = lin & 7;
      const int fi = PG((r >> 4) * 128 + g * 16 + (r & 15));
      Ks[fi] = *(const half8*)(k_ + bhoff + (size_t)(kc + r) * 64 + g * 8);
      Vs[fi] = *(const half8*)(vt + bhoff + (size_t)r * 512 + kc + g * 8);
    }
    if (tid < 128)
      Ms[tid >> 1][tid & 1] =
          pk[((size_t)((bh >> 2) << 9) + q0 + (tid >> 1)) * 16 + (kc >> 5) + (tid & 1)];
    __syncthreads();
    const int ga0 = (w * 8 + quad) * 17 + l15;
    const int ga1 = (w * 8 + quad + 4) * 17 + l15;
    const half8 ah0 = Ks[ga0], ah1 = Ks[ga1];
    #pragma unroll
    for (int ns = 0; ns < 4; ++ns) {
      float4v s = (float4v){0.f, 0.f, 0.f, 0.f};
      s = MFMA16(ah0, qf[ns][0], s);
      s = MFMA16(ah1, qf[ns][1], s);
      const int q = ns * 16 + l15;
      const unsigned long long mrow = *(const unsigned long long*)&Ms[q][0];
      const unsigned mbits = (unsigned)(mrow >> (w * 16 + quad * 4)) & 15u;
      half4 h4;
      #pragma unroll
      for (int r = 0; r < 4; ++r) {
        const float pe = ((mbits >> r) & 1u) ? __expf(s[r] * 0.125f) : 0.f;
        h4[r] = (_Float16)pe;
        lsw[ns] += pe;
      }
      const int hb = ((ns * 8 + w * 2 + (quad >> 1)) * 17 + l15) * 8 + (quad & 1) * 4;
      *(half4*)((_Float16*)QP + hb) = h4;
    }
    __syncthreads();
    const half8 vh0 = Vs[ga0], vh1 = Vs[ga1];
    #pragma unroll
    for (int ns = 0; ns < 4; ++ns) {
      const int pb0 = (ns * 8 + quad) * 17 + l15;
      const int pb1 = (ns * 8 + quad + 4) * 17 + l15;
      oacc[ns] = MFMA16(vh0, QP[pb0], oacc[ns]);
      oacc[ns] = MFMA16(vh1, QP[pb1], oacc[ns]);
    }
  }
  #pragma unroll
  for (int ns = 0; ns < 4; ++ns) {
    lsw[ns] += __shfl_xor(lsw[ns], 16);
    lsw[ns] += __shfl_xor(lsw[ns], 32);
  }
  __syncthreads();
  if (quad == 0) {
    #pragma unroll
    for (int ns = 0; ns < 4; ++ns) Ps[w][ns * 16 + l15] = lsw[ns];
  }
  __syncthreads();
  if (tid < 64) lsum[tid] = Ps[0][tid] + Ps[1][tid] + Ps[2][tid] + Ps[3][tid];
  __syncthreads();
  const int b = bh >> 2, h = bh & 3;
  #pragma unroll
  for (int ns = 0; ns < 4; ++ns) {
    const int q = ns * 16 + l15;
    const float inv = 1.0f / lsum[q];
    half4 h4;
    #pragma unroll
    for (int r = 0; r < 4; ++r) h4[r] = (_Float16)(oacc[ns][r] * inv);
    *(half4*)(o + ((size_t)(b * SLEN + q0 + q)) * DMOD + h * HDIM + w * 16 + quad * 4) = h4;
  }
}

// ---------------- layer norm + zero invalid rows ----------------
__global__ __launch_bounds__(256) void k_ln(
    const float* __restrict__ Y, const int* __restrict__ lengths,
    const float* __restrict__ g, const float* __restrict__ bb,
    float* __restrict__ out) {
  const int row = blockIdx.x * 4 + (threadIdx.x >> 6);
  const int lane = threadIdx.x & 63;
  const int b = row >> 9, s = row & 511;
  const float* yr = Y + (size_t)row * DMOD;
  float v[4];
  *(float4*)v = *(const float4*)(yr + lane * 4);
  float sum = v[0] + v[1] + v[2] + v[3];
  #pragma unroll
  for (int off = 32; off > 0; off >>= 1) sum += __shfl_xor(sum, off);
  const float mu = sum * (1.0f / DMOD);
  float vs = 0.f;
  #pragma unroll
  for (int i = 0; i < 4; ++i) { const float dx = v[i] - mu; vs += dx * dx; }
  #pragma unroll
  for (int off = 32; off > 0; off >>= 1) vs += __shfl_xor(vs, off);
  const float inv = rsqrtf(vs * (1.0f / DMOD) + 1e-5f);
  const bool valid = s < lengths[b];
  float gg[4], bv[4], ov[4];
  *(float4*)gg = *(const float4*)(g + lane * 4);
  *(float4*)bv = *(const float4*)(bb + lane * 4);
  #pragma unroll
  for (int i = 0; i < 4; ++i)
    ov[i] = valid ? ((v[i] - mu) * inv * gg[i] + bv[i]) : 0.f;
  *(float4*)(out + (size_t)row * DMOD + lane * 4) = *(float4*)ov;
}

// ---------------- triangular temporal pooling, 4 bins fused, s-chunked ----------
__global__ __launch_bounds__(256) void k_pool(
    const float* __restrict__ X, const int* __restrict__ lengths,
    float* __restrict__ Up) {
  const int b = blockIdx.x;
  const int c = blockIdx.y;
  const int d = threadIdx.x;
  const float inv4 = 4.0f / (float)lengths[b];
  float a0 = 0.f, a1 = 0.f, a2 = 0.f, a3 = 0.f;
  for (int s = c * 128; s < c * 128 + 128; ++s) {
    const float sv = (float)(s + 1) * inv4;
    const float xv = X[((size_t)b * SLEN + s) * DMOD + d];
    float t;
    t = 1.0f - fabsf(sv - 1.0f) * 0.25f; a0 += t * t * xv;
    t = 1.0f - fabsf(sv - 2.0f) * 0.25f; a1 += t * t * xv;
    t = 1.0f - fabsf(sv - 3.0f) * 0.25f; a2 += t * t * xv;
    t = 1.0f - fabsf(sv - 4.0f) * 0.25f; a3 += t * t * xv;
  }
  float* up = Up + (((size_t)b * 4 + c) * 4) * DMOD + d;
  up[0 * DMOD] = a0; up[1 * DMOD] = a1; up[2 * DMOD] = a2; up[3 * DMOD] = a3;
}

// ---------------- final [32,1024] @ [1024,2]^T + bias ---------------------------
__global__ __launch_bounds__(256) void k_out(
    const float* __restrict__ Up, const float* __restrict__ ow,
    const float* __restrict__ ob, float* __restrict__ out) {
  const int tid = threadIdx.x;
  const int pair = tid >> 2;
  const int part = tid & 3;
  const int b = pair >> 1, i = pair & 1;
  const float* upb = Up + ((size_t)b * 16 + part) * DMOD;
  const float* wb = ow + (size_t)i * 1024 + part * DMOD;
  float acc = 0.f;
  for (int d = 0; d < DMOD; d += 4) {
    const float4 u0 = *(const float4*)(upb + d);
    const float4 u1 = *(const float4*)(upb + 4 * DMOD + d);
    const float4 u2 = *(const float4*)(upb + 8 * DMOD + d);
    const float4 u3 = *(const float4*)(upb + 12 * DMOD + d);
    const float4 w = *(const float4*)(wb + d);
    acc += (u0.x + u1.x + u2.x + u3.x) * w.x + (u0.y + u1.y + u2.y + u3.y) * w.y +
           (u0.z + u1.z + u2.z + u3.z) * w.z + (u0.w + u1.w + u2.w + u3.w) * w.w;
  }
  acc += __shfl_xor(acc, 1);
  acc += __shfl_xor(acc, 2);
  if (part == 0) out[b * 2 + i] = acc + ob[i];
}

extern "C" void kernel_launch(void* const* d_in, const int* in_sizes, int n_in,
                              void* d_out, int out_size, void* d_ws, size_t ws_size,
                              hipStream_t stream) {
  const int* seqs     = (const int*)d_in[0];
  const int* masks    = (const int*)d_in[1];
  const int* lengths  = (const int*)d_in[2];
  const float* emb    = (const float*)d_in[5];
  const float* bias   = (const float*)d_in[6];
  const float* pe     = (const float*)d_in[7];
  const float* Wq     = (const float*)d_in[8];
  const float* Wk     = (const float*)d_in[9];
  const float* Wv     = (const float*)d_in[10];
  const float* Wfc    = (const float*)d_in[11];
  const float* ln_g   = (const float*)d_in[12];
  const float* ln_b   = (const float*)d_in[13];
  const float* out_w  = (const float*)d_in[14];
  const float* out_b  = (const float*)d_in[15];
  float* outp = (float*)d_out;

  const size_t NE = (size_t)BSZ * SLEN * DMOD;   // 4,194,304
  _Float16* q = (_Float16*)d_ws;
  _Float16* k = q + NE;
  _Float16* v = k + NE;
  _Float16* vt = v + NE;
  _Float16* x = vt + NE;
  _Float16* o = x + NE;
  _Float16* wh = o + NE;                         // 4*65536 halfs
  unsigned int* pk = (unsigned int*)(wh + 4 * 65536);
  float* Up = (float*)(pk + BSZ * SLEN * 16);
  float* y = (float*)q;                          // alias: q,k dead after attn (16 MB)

  k_embed<<<BSZ * SLEN / 4, 256, 0, stream>>>(seqs, lengths, emb, bias, pe, x);
  k_wsplit<<<dim3(32, 4), 256, 0, stream>>>(Wq, Wk, Wv, Wfc, wh);
  k_maskpack<<<BSZ * SLEN, 256, 0, stream>>>(masks, pk);
  k_gemm_qkv<<<dim3(128, 2, 3), 256, 0, stream>>>(x, wh, q, k, v);
  k_vt<<<dim3(BSZ * NH, 2), 256, 0, stream>>>(v, vt);
  k_attn<<<dim3(BSZ * NH, SLEN / 64), 256, 0, stream>>>(q, k, vt, pk, o);
  k_gemm_fc<<<dim3(128, 2), 256, 0, stream>>>(o, wh + 3 * 65536, y, x);
  k_ln<<<BSZ * SLEN / 4, 256, 0, stream>>>(y, lengths, ln_g, ln_b, y);
  k_pool<<<dim3(BSZ, 4), 256, 0, stream>>>(y, lengths, Up);
  k_out<<<1, 256, 0, stream>>>(Up, out_w, out_b, outp);
}